// Round 3
// baseline (1076.828 us; speedup 1.0000x reference)
//
#include <hip/hip_runtime.h>
#include <math.h>

#define NPTS 1024
#define DIM 32
#define NPAIR 16   // B*NW
#define GRID 512

typedef __attribute__((ext_vector_type(8))) short short8;
typedef __attribute__((ext_vector_type(4))) float f32x4;
typedef __attribute__((ext_vector_type(8))) unsigned short ushort8v;
typedef unsigned short u16;
typedef unsigned char u8;

__device__ __forceinline__ u16 bf16_rne(float v) {
    unsigned u = __float_as_uint(v);
    return (u16)((u + 0x7fffu + ((u >> 16) & 1u)) >> 16);
}
__device__ __forceinline__ float bf16_to_f32(u16 b) {
    return __uint_as_float(((unsigned)b) << 16);
}

// u8 W (0..255) -> bf16 short8. Integers <=255 are exact in bf16.
__device__ __forceinline__ short8 unpack_w8(unsigned lo, unsigned hi) {
    short8 r;
#pragma unroll
    for (int j = 0; j < 4; j++) {
        float f0 = (float)((lo >> (8 * j)) & 0xffu);
        float f1 = (float)((hi >> (8 * j)) & 0xffu);
        r[j]     = (short)(__float_as_uint(f0) >> 16);
        r[j + 4] = (short)(__float_as_uint(f1) >> 16);
    }
    return r;
}

// ---- grid-wide barrier for the persistent mega kernel ----
// All 512 blocks are co-resident (2 blocks/CU guaranteed by launch_bounds(512,4)
// VGPR<=128 + 51.4KB LDS). __threadfence() at agent scope emits the L2
// writeback/invalidate required across non-coherent per-XCD L2s; the counter
// atomics execute at the coherence point (agent scope).
__device__ __forceinline__ void gsync(unsigned* ctr, int id) {
    __syncthreads();
    if (threadIdx.x == 0) {
        __threadfence();  // release: flush this XCD's L2 (all co-located blocks' prior writes)
        __hip_atomic_fetch_add(&ctr[id], 1u, __ATOMIC_RELAXED, __HIP_MEMORY_SCOPE_AGENT);
        while (__hip_atomic_load(&ctr[id], __ATOMIC_RELAXED, __HIP_MEMORY_SCOPE_AGENT) < (unsigned)GRID)
            __builtin_amdgcn_s_sleep(2);
        __threadfence();  // acquire: invalidate stale L1/L2 lines before next stage's reads
    }
    __syncthreads();
}

// ============ build X + sqX + XT hi/lo (bf16 transposed) + zero deg + zero barrier ctrs ============
// grid (16 ntiles, NPAIR), block 256
__global__ __launch_bounds__(256) void build_X(const float* __restrict__ pc,
                                               const float* __restrict__ alphas,
                                               float* __restrict__ X,
                                               float* __restrict__ sqX,
                                               float* __restrict__ deg,
                                               u16* __restrict__ hiT,
                                               u16* __restrict__ loT,
                                               unsigned* __restrict__ ctr) {
    __shared__ float S[DIM][68];
    int pair = blockIdx.y, n0 = blockIdx.x * 64, tid = threadIdx.x;
    int b = pair >> 2, w = pair & 3;
    if (blockIdx.x == 0 && blockIdx.y == 0 && tid < 64) ctr[tid] = 0;  // barrier counters
    for (int e = tid; e < 512; e += 256) {
        int e4 = e * 4;
        int dn = e4 >> 5, dq = e4 & 31;
        float4 p = *(const float4*)&pc[((size_t)b * NPTS + n0 + dn) * DIM + dq];
        float4 al = *(const float4*)&alphas[w * DIM + dq];
        float4 x = make_float4(p.x * al.x, p.y * al.y, p.z * al.z, p.w * al.w);
        *(float4*)&X[((size_t)pair * NPTS + n0 + dn) * DIM + dq] = x;
        S[dq][dn] = x.x; S[dq + 1][dn] = x.y; S[dq + 2][dn] = x.z; S[dq + 3][dn] = x.w;
    }
    __syncthreads();
    if (tid < 64) {
        float s = 0.f;
#pragma unroll
        for (int d = 0; d < DIM; d++) { float v = S[d][tid]; s += v * v; }
        sqX[pair * NPTS + n0 + tid] = s;
        deg[pair * NPTS + n0 + tid] = 0.0f;
    }
    for (int idx = tid; idx < DIM * 4; idx += 256) {
        int row = idx >> 2, nq = (idx & 3) * 16;
        ushort8v hv[2], lv[2];
#pragma unroll
        for (int i = 0; i < 16; i++) {
            float v = S[row][nq + i];
            u16 hb = bf16_rne(v);
            hv[i >> 3][i & 7] = hb;
            lv[i >> 3][i & 7] = bf16_rne(v - bf16_to_f32(hb));
        }
        size_t o = ((size_t)pair * DIM + row) * NPTS + n0 + nq;
        *(ushort8v*)(hiT + o) = hv[0]; *(ushort8v*)(hiT + o + 8) = hv[1];
        *(ushort8v*)(loT + o) = lv[0]; *(ushort8v*)(loT + o + 8) = lv[1];
    }
}

// ============ single-pass W: W u8 (q = round(255*W)); deg = sum of quantized q ============
// grid 1024 blocks flat: xcd = b&7 -> pair = xcd*2 + (loc&1); block 256
__global__ __launch_bounds__(256, 4) void W_kernel(const float* __restrict__ X,
                                                   const float* __restrict__ sqX,
                                                   const float* __restrict__ sigp,
                                                   float* __restrict__ deg,
                                                   u8* __restrict__ W8) {
    int bid = blockIdx.x;
    int xcd = bid & 7, loc = bid >> 3;          // loc 0..127
    int pair = xcd * 2 + (loc & 1);
    int j0 = ((loc >> 1) & 3) * 256;
    int i0 = (loc >> 3) * 64;
    float rsig = -1.0f / (*sigp);
    const float* Xp = X + (size_t)pair * NPTS * DIM;

    __shared__ float XiT[DIM][68];
    __shared__ float XjT[DIM][68];
    __shared__ float sqjS[64];

    int tid = threadIdx.x;
    int cx = tid & 15, ry = tid >> 4;

    {
        int r = tid & 63, dgb = (tid >> 6) * 4;
#pragma unroll
        for (int p = 0; p < 2; p++) {
            int dg = dgb + p * 16;
            float4 v = *(const float4*)&Xp[(size_t)(i0 + r) * DIM + dg];
            XiT[dg][r] = v.x; XiT[dg + 1][r] = v.y; XiT[dg + 2][r] = v.z; XiT[dg + 3][r] = v.w;
        }
    }
    float sqi[4];
#pragma unroll
    for (int a = 0; a < 4; a++) sqi[a] = sqX[pair * NPTS + i0 + ry * 4 + a];

    float rs[4] = {0.f, 0.f, 0.f, 0.f};
#pragma unroll 1
    for (int jt = 0; jt < 256; jt += 64) {
        __syncthreads();
        {
            int r = tid & 63, dgb = (tid >> 6) * 4;
#pragma unroll
            for (int p = 0; p < 2; p++) {
                int dg = dgb + p * 16;
                float4 v = *(const float4*)&Xp[(size_t)(j0 + jt + r) * DIM + dg];
                XjT[dg][r] = v.x; XjT[dg + 1][r] = v.y; XjT[dg + 2][r] = v.z; XjT[dg + 3][r] = v.w;
            }
        }
        if (tid < 64) sqjS[tid] = sqX[pair * NPTS + j0 + jt + tid];
        __syncthreads();

        float dot[4][4] = {};
#pragma unroll
        for (int d = 0; d < DIM; d++) {
            float4 a = *(const float4*)&XiT[d][ry * 4];
            float4 b = *(const float4*)&XjT[d][cx * 4];
            dot[0][0] += a.x * b.x; dot[0][1] += a.x * b.y; dot[0][2] += a.x * b.z; dot[0][3] += a.x * b.w;
            dot[1][0] += a.y * b.x; dot[1][1] += a.y * b.y; dot[1][2] += a.y * b.z; dot[1][3] += a.y * b.w;
            dot[2][0] += a.z * b.x; dot[2][1] += a.z * b.y; dot[2][2] += a.z * b.z; dot[2][3] += a.z * b.w;
            dot[3][0] += a.w * b.x; dot[3][1] += a.w * b.y; dot[3][2] += a.w * b.z; dot[3][3] += a.w * b.w;
        }
#pragma unroll
        for (int a = 0; a < 4; a++) {
            int i = i0 + ry * 4 + a;
            int jb = j0 + jt + cx * 4;
            unsigned qw = 0;
#pragma unroll
            for (int bb = 0; bb < 4; bb++) {
                float Dm = sqi[a] + sqjS[cx * 4 + bb] - 2.0f * dot[a][bb];
                float K = __expf(Dm * rsig);
                float Wv = (K >= 0.5f) ? K : 0.0f;
                unsigned q = (unsigned)fmaf(Wv, 255.0f, 0.5f);   // 0 or 128..255
                rs[a] += (float)q;                                // deg tracks the QUANTIZED sum
                qw |= q << (8 * bb);
            }
            *(unsigned*)(W8 + ((size_t)pair * NPTS + i) * NPTS + jb) = qw;
        }
    }
#pragma unroll
    for (int a = 0; a < 4; a++) {
        float s = rs[a];
        s += __shfl_xor(s, 1); s += __shfl_xor(s, 2);
        s += __shfl_xor(s, 4); s += __shfl_xor(s, 8);
        if (cx == 0) atomicAdd(&deg[pair * NPTS + i0 + ry * 4 + a], s);
    }
}

// ============ one apply stage inside the mega kernel (same math as apply_fused) ============
template <int DC>
__device__ __forceinline__ void apply_stage(char* ldsu, int pair, int r0, int tid,
                                            const u8* W8, const u16* Yhi, const u16* Ylo,
                                            const float* deg,
                                            const float* prevF, int prevStride, int prevOff,
                                            float* dstF, int dstStride, int dstOff,
                                            float* sliceF,
                                            u16* hiT, u16* loT, int tC0, int tCN) {
    constexpr int NT = DC / 16;
    constexpr int SP = DC + 4;
    float (*S)[32][SP] = (float (*)[32][SP])ldsu;
    float* rdegS = (float*)(ldsu + (size_t)4 * 32 * SP * 4);
    int wv = tid >> 6, lane = tid & 63;
    int m = lane & 15, quad = lane >> 4;
    int kb = wv * 128;

    if (tid < 32) rdegS[tid] = 0.5f / deg[pair * NPTS + r0 + tid];

    size_t aoff = ((size_t)pair * NPTS + r0 + m) * NPTS + kb + quad * 8;   // byte offset (u8 W)
    size_t boff = ((size_t)pair * DC + m) * NPTS + kb + quad * 8;

    f32x4 acc[2][NT];
#pragma unroll
    for (int mt = 0; mt < 2; mt++)
#pragma unroll
        for (int nt = 0; nt < NT; nt++)
#pragma unroll
            for (int i = 0; i < 4; i++) acc[mt][nt][i] = 0.0f;

#pragma unroll 2
    for (int c = 0; c < 4; c++) {
        int ko = c * 32;
        uint2 a0q = *(const uint2*)(W8 + aoff + ko);
        uint2 a1q = *(const uint2*)(W8 + aoff + 16 * NPTS + ko);
        short8 a0h = unpack_w8(a0q.x, a0q.y);
        short8 a1h = unpack_w8(a1q.x, a1q.y);
#pragma unroll
        for (int nt = 0; nt < NT; nt++) {
            short8 bh = *(const short8*)(Yhi + boff + (size_t)nt * 16 * NPTS + ko);
            short8 bl = *(const short8*)(Ylo + boff + (size_t)nt * 16 * NPTS + ko);
            acc[0][nt] = __builtin_amdgcn_mfma_f32_16x16x32_bf16(a0h, bh, acc[0][nt], 0, 0, 0);
            acc[0][nt] = __builtin_amdgcn_mfma_f32_16x16x32_bf16(a0h, bl, acc[0][nt], 0, 0, 0);
            acc[1][nt] = __builtin_amdgcn_mfma_f32_16x16x32_bf16(a1h, bh, acc[1][nt], 0, 0, 0);
            acc[1][nt] = __builtin_amdgcn_mfma_f32_16x16x32_bf16(a1h, bl, acc[1][nt], 0, 0, 0);
        }
    }

    // phase 1a: waves 0-3 deposit partial tiles
    if (wv < 4) {
#pragma unroll
        for (int mt = 0; mt < 2; mt++)
#pragma unroll
            for (int nt = 0; nt < NT; nt++)
#pragma unroll
                for (int i = 0; i < 4; i++)
                    S[wv][mt * 16 + quad * 4 + i][nt * 16 + m] = acc[mt][nt][i];
    }
    __syncthreads();
    // phase 1b: waves 4-7 add into planes 0-3
    if (wv >= 4) {
#pragma unroll
        for (int mt = 0; mt < 2; mt++)
#pragma unroll
            for (int nt = 0; nt < NT; nt++)
#pragma unroll
                for (int i = 0; i < 4; i++)
                    S[wv - 4][mt * 16 + quad * 4 + i][nt * 16 + m] += acc[mt][nt][i];
    }
    __syncthreads();

    // phase 2: sum planes, epilogue O = 0.5*prev + rdeg*sum, write fp32, stash in S[0]
    constexpr int E2 = 32 * DC / 4;
    for (int e = tid; e < E2; e += 512) {
        int e4 = e * 4;
        int n = e4 / DC, d = e4 % DC;
        float4 s0 = *(const float4*)&S[0][n][d];
        float4 s1 = *(const float4*)&S[1][n][d];
        float4 s2 = *(const float4*)&S[2][n][d];
        float4 s3 = *(const float4*)&S[3][n][d];
        float4 pv = *(const float4*)&prevF[((size_t)pair * NPTS + r0 + n) * prevStride + prevOff + d];
        float r = rdegS[n];
        float4 o = make_float4(0.5f * pv.x + r * (s0.x + s1.x + s2.x + s3.x),
                               0.5f * pv.y + r * (s0.y + s1.y + s2.y + s3.y),
                               0.5f * pv.z + r * (s0.z + s1.z + s2.z + s3.z),
                               0.5f * pv.w + r * (s0.w + s1.w + s2.w + s3.w));
        *(float4*)&dstF[((size_t)pair * NPTS + r0 + n) * dstStride + dstOff + d] = o;
        if (sliceF && d >= 32 && d < 64)
            *(float4*)&sliceF[((size_t)pair * NPTS + r0 + n) * 32 + (d - 32)] = o;
        *(float4*)&S[0][n][d] = o;
    }
    __syncthreads();

    // phase 3: transposed bf16 hi/lo operand for the next step
    if (hiT) {
        for (int e = tid; e < tCN * 4; e += 512) {
            int row = e >> 2, nq = (e & 3) * 8;
            ushort8v hv, lv;
#pragma unroll
            for (int j = 0; j < 8; j++) {
                float v = S[0][nq + j][tC0 + row];
                u16 hb = bf16_rne(v);
                hv[j] = hb;
                lv[j] = bf16_rne(v - bf16_to_f32(hb));
            }
            size_t o = ((size_t)pair * tCN + row) * NPTS + r0 + nq;
            *(ushort8v*)(hiT + o) = hv;
            *(ushort8v*)(loT + o) = lv;
        }
    }
}

// ============ persistent mega kernel: 12 applies + build_M0 + pooling, grid barriers between ============
// grid 512 flat (pair = (b&7)*2 + ((b>>3)&1), rowtile = b>>4), block 512, 2 blocks/CU resident
__global__ __launch_bounds__(512, 4) void mega(const u8* __restrict__ W8,
                                               const float* __restrict__ deg,
                                               const float* __restrict__ X,
                                               float* __restrict__ A1, float* __restrict__ A2,
                                               float* __restrict__ A3,
                                               float* __restrict__ M0, float* __restrict__ M2p,
                                               float* __restrict__ M4f, float* __restrict__ Z8,
                                               float* __restrict__ F96a, float* __restrict__ F96b,
                                               u16* __restrict__ T32a_h, u16* __restrict__ T32a_l,
                                               u16* __restrict__ T32b_h, u16* __restrict__ T32b_l,
                                               u16* __restrict__ T96a_h, u16* __restrict__ T96a_l,
                                               u16* __restrict__ T96b_h, u16* __restrict__ T96b_l,
                                               float* __restrict__ poolP,
                                               float* __restrict__ out,
                                               unsigned* __restrict__ ctr) {
    __shared__ __align__(16) char ldsu[51456];   // max stage need: (4*32*100 + 32)*4 = 51328
    int bid = blockIdx.x;
    int pair = (bid & 7) * 2 + ((bid >> 3) & 1);
    int r0 = (bid >> 4) * 32;
    int rt = bid >> 4;
    int tid = threadIdx.x;

    // ---- A-chain (D=32) ----
    apply_stage<32>(ldsu, pair, r0, tid, W8, T32a_h, T32a_l, deg,
                    X, 32, 0, A1, 32, 0, nullptr, T32b_h, T32b_l, 0, 32);
    gsync(ctr, 0);
    apply_stage<32>(ldsu, pair, r0, tid, W8, T32b_h, T32b_l, deg,
                    A1, 32, 0, A2, 32, 0, nullptr, T32a_h, T32a_l, 0, 32);
    gsync(ctr, 1);
    apply_stage<32>(ldsu, pair, r0, tid, W8, T32a_h, T32a_l, deg,
                    A2, 32, 0, A3, 32, 0, nullptr, T32b_h, T32b_l, 0, 32);
    gsync(ctr, 2);
    apply_stage<32>(ldsu, pair, r0, tid, W8, T32b_h, T32b_l, deg,
                    A3, 32, 0, M0, 96, 0, nullptr, nullptr, nullptr, 0, 32);
    gsync(ctr, 3);

    // ---- build_M0 stage: M0 cols 32..95 fp32 + full M0T hi/lo (this block's 32 points) ----
    {
        float (*SB)[34] = (float (*)[34])ldsu;   // 96 x 34 floats = 13056 B
        if (tid < 256) {
            int dn = tid >> 3;            // point 0..31
            int dq = (tid & 7) * 4;       // feature quad
            size_t pn = (size_t)pair * NPTS + r0 + dn;
            float4 a1 = *(const float4*)&A1[pn * 32 + dq];
            float4 a2 = *(const float4*)&A2[pn * 32 + dq];
            float4 t4 = *(const float4*)&M0[pn * 96 + dq];
            float4 f0 = make_float4(fabsf(a1.x - a2.x), fabsf(a1.y - a2.y), fabsf(a1.z - a2.z), fabsf(a1.w - a2.w));
            float4 f1 = make_float4(fabsf(a2.x - t4.x), fabsf(a2.y - t4.y), fabsf(a2.z - t4.z), fabsf(a2.w - t4.w));
            *(float4*)&M0[pn * 96 + 32 + dq] = f0;
            *(float4*)&M0[pn * 96 + 64 + dq] = f1;
            SB[dq][dn] = t4.x; SB[dq + 1][dn] = t4.y; SB[dq + 2][dn] = t4.z; SB[dq + 3][dn] = t4.w;
            SB[32 + dq][dn] = f0.x; SB[33 + dq][dn] = f0.y; SB[34 + dq][dn] = f0.z; SB[35 + dq][dn] = f0.w;
            SB[64 + dq][dn] = f1.x; SB[65 + dq][dn] = f1.y; SB[66 + dq][dn] = f1.z; SB[67 + dq][dn] = f1.w;
        }
        __syncthreads();
        if (tid < 384) {
            int row = tid >> 2, nq = (tid & 3) * 8;
            ushort8v hv, lv;
#pragma unroll
            for (int j = 0; j < 8; j++) {
                float v = SB[row][nq + j];
                u16 hb = bf16_rne(v);
                hv[j] = hb;
                lv[j] = bf16_rne(v - bf16_to_f32(hb));
            }
            size_t o = ((size_t)pair * 96 + row) * NPTS + r0 + nq;
            *(ushort8v*)(T96a_h + o) = hv;
            *(ushort8v*)(T96a_l + o) = lv;
        }
    }
    gsync(ctr, 4);

    // ---- M-chain (D=96) ----
    apply_stage<96>(ldsu, pair, r0, tid, W8, T96a_h, T96a_l, deg,
                    M0, 96, 0, F96a, 96, 0, nullptr, T96b_h, T96b_l, 0, 96);
    gsync(ctr, 5);
    apply_stage<96>(ldsu, pair, r0, tid, W8, T96b_h, T96b_l, deg,
                    F96a, 96, 0, F96b, 96, 0, M2p, T96a_h, T96a_l, 0, 96);
    gsync(ctr, 6);
    apply_stage<96>(ldsu, pair, r0, tid, W8, T96a_h, T96a_l, deg,
                    F96b, 96, 0, F96a, 96, 0, nullptr, T96b_h, T96b_l, 0, 96);
    gsync(ctr, 7);
    apply_stage<96>(ldsu, pair, r0, tid, W8, T96b_h, T96b_l, deg,
                    F96a, 96, 0, M4f, 96, 0, nullptr, T96a_h, T96a_l, 32, 64);   // T64a = T96a
    gsync(ctr, 8);

    // ---- N-chain (D=64) ----
    apply_stage<64>(ldsu, pair, r0, tid, W8, T96a_h, T96a_l, deg,
                    M4f, 96, 32, F96a, 64, 0, nullptr, T96b_h, T96b_l, 0, 64);
    gsync(ctr, 9);
    apply_stage<64>(ldsu, pair, r0, tid, W8, T96b_h, T96b_l, deg,
                    F96a, 64, 0, F96b, 64, 0, nullptr, T96a_h, T96a_l, 0, 64);
    gsync(ctr, 10);
    apply_stage<64>(ldsu, pair, r0, tid, W8, T96a_h, T96a_l, deg,
                    F96b, 64, 0, F96a, 64, 0, nullptr, T96b_h, T96b_l, 0, 64);
    gsync(ctr, 11);
    apply_stage<64>(ldsu, pair, r0, tid, W8, T96b_h, T96b_l, deg,
                    F96a, 64, 0, Z8, 64, 0, nullptr, nullptr, nullptr, 0, 64);
    gsync(ctr, 12);

    // ---- pooling partials: this block sums its 32 points for all 7 groups x 32 dims ----
    {
        float (*PP)[2][32] = (float (*)[2][32])ldsu;   // 7 x 2 x 32 floats
        if (tid < 448) {
            int g = tid >> 6;            // wave-uniform group 0..6
            int h = (tid >> 5) & 1;
            int d = tid & 31;
            float s = 0.0f;
#pragma unroll 4
            for (int k = 0; k < 16; k++) {
                int n = r0 + h * 16 + k;
                size_t pn = (size_t)pair * NPTS + n;
                float v = 0.0f;
                switch (g) {
                    case 0: v = X[pn * 32 + d]; break;
                    case 1: v = M0[pn * 96 + 32 + d]; break;
                    case 2: v = M0[pn * 96 + 64 + d]; break;
                    case 3: v = fabsf(M0[pn * 96 + d] - M4f[pn * 96 + d]); break;
                    case 4: v = fabsf(M2p[pn * 32 + d] - M4f[pn * 96 + 32 + d]); break;
                    case 5: v = fabsf(M4f[pn * 96 + 32 + d] - Z8[pn * 64 + d]); break;
                    case 6: v = fabsf(M4f[pn * 96 + 64 + d] - Z8[pn * 64 + 32 + d]); break;
                }
                s += v;
            }
            PP[g][h][d] = s;
        }
        __syncthreads();
        if (tid < 224) {
            int g = tid >> 5, d = tid & 31;
            poolP[(((size_t)g * NPAIR + pair) * 32 + rt) * 32 + d] = PP[g][0][d] + PP[g][1][d];
        }
    }
    gsync(ctr, 13);

    // ---- final reduce: blocks 0..15 own one pair each ----
    if (bid < NPAIR && tid < 224) {
        int g = tid >> 5, d = tid & 31;
        float s = 0.0f;
#pragma unroll 8
        for (int r = 0; r < 32; r++)
            s += poolP[(((size_t)g * NPAIR + bid) * 32 + r) * 32 + d];
        out[(size_t)bid * 224 + tid] = s * (1.0f / 1024.0f);
    }
}

extern "C" void kernel_launch(void* const* d_in, const int* in_sizes, int n_in,
                              void* d_out, int out_size, void* d_ws, size_t ws_size,
                              hipStream_t stream) {
    const float* pc     = (const float*)d_in[0];
    const float* alphas = (const float*)d_in[1];
    const float* sigp   = (const float*)d_in[2];
    float* out = (float*)d_out;
    float* ws = (float*)d_ws;

    // ---- workspace layout (~59 MB) ----
    float* X    = ws;                         // 524288
    float* sqX  = X + 524288;                 // 16384
    float* deg  = sqX + 16384;                // 16384
    u8* W8 = (u8*)(deg + 16384);              // 16777216 u8 (q = round(255*W))
    float* A1   = (float*)(W8 + 16777216);    // 524288
    float* A2   = A1 + 524288;                // 524288
    u16* T32a_h = (u16*)(A2 + 524288);        // 524288 u16 each
    u16* T32a_l = T32a_h + 524288;
    u16* T32b_h = T32a_l + 524288;
    u16* T32b_l = T32b_h + 524288;
    float* F96b = A1;                         // overlay (A1,A2,T32a dead by then)... kept distinct region below instead
    float* M0   = (float*)(T32b_l + 524288);  // 1572864
    float* M2p  = M0 + 1572864;               // 524288
    float* M4f  = M2p + 524288;               // 1572864
    float* Z8   = M4f + 1572864;              // 1048576
    float* F96a = Z8 + 1048576;               // 1572864  (also A3 overlay before M-chain)
    float* A3   = F96a;
    u16* T96a_h = (u16*)(F96a + 1572864);     // 1572864 u16 each
    u16* T96a_l = T96a_h + 1572864;
    u16* T96b_h = T96a_l + 1572864;
    u16* T96b_l = T96b_h + 1572864;
    float* poolP = (float*)(T96b_l + 1572864); // 7*16*32*32 = 114688 floats
    unsigned* ctr = (unsigned*)(poolP + 114688); // 64 barrier counters

    build_X<<<dim3(16, NPAIR), dim3(256), 0, stream>>>(pc, alphas, X, sqX, deg, T32a_h, T32a_l, ctr);
    W_kernel<<<dim3(1024), dim3(256), 0, stream>>>(X, sqX, sigp, deg, W8);
    mega<<<dim3(GRID), dim3(512), 0, stream>>>(W8, deg, X, A1, A2, A3,
                                               M0, M2p, M4f, Z8, F96a, F96b,
                                               T32a_h, T32a_l, T32b_h, T32b_l,
                                               T96a_h, T96a_l, T96b_h, T96b_l,
                                               poolP, out, ctr);
}

// Round 4
// 367.685 us; speedup vs baseline: 2.9287x; 2.9287x over previous
//
#include <hip/hip_runtime.h>
#include <math.h>

#define NPTS 1024
#define DIM 32
#define NPAIR 16   // B*NW

typedef __attribute__((ext_vector_type(8))) short short8;
typedef __attribute__((ext_vector_type(4))) float f32x4;
typedef __attribute__((ext_vector_type(8))) unsigned short ushort8v;
typedef unsigned short u16;
typedef unsigned char u8;

__device__ __forceinline__ u16 bf16_rne(float v) {
    unsigned u = __float_as_uint(v);
    return (u16)((u + 0x7fffu + ((u >> 16) & 1u)) >> 16);
}
__device__ __forceinline__ float bf16_to_f32(u16 b) {
    return __uint_as_float(((unsigned)b) << 16);
}

// u8 W (0..255) -> bf16 short8. Integers <=255 are exact in bf16.
__device__ __forceinline__ short8 unpack_w8(unsigned lo, unsigned hi) {
    short8 r;
#pragma unroll
    for (int j = 0; j < 4; j++) {
        float f0 = (float)((lo >> (8 * j)) & 0xffu);
        float f1 = (float)((hi >> (8 * j)) & 0xffu);
        r[j]     = (short)(__float_as_uint(f0) >> 16);
        r[j + 4] = (short)(__float_as_uint(f1) >> 16);
    }
    return r;
}

// ============ build_X: X + sqX + XT hi/lo + zero deg + pool group-0 partials ============
// grid (16 ntiles, NPAIR), block 256
__global__ __launch_bounds__(256) void build_X(const float* __restrict__ pc,
                                               const float* __restrict__ alphas,
                                               float* __restrict__ X,
                                               float* __restrict__ sqX,
                                               float* __restrict__ deg,
                                               u16* __restrict__ hiT,
                                               u16* __restrict__ loT,
                                               float* __restrict__ poolP) {
    __shared__ float S[DIM][68];
    int pair = blockIdx.y, n0 = blockIdx.x * 64, tid = threadIdx.x;
    int b = pair >> 2, w = pair & 3;
    for (int e = tid; e < 512; e += 256) {
        int e4 = e * 4;
        int dn = e4 >> 5, dq = e4 & 31;
        float4 p = *(const float4*)&pc[((size_t)b * NPTS + n0 + dn) * DIM + dq];
        float4 al = *(const float4*)&alphas[w * DIM + dq];
        float4 x = make_float4(p.x * al.x, p.y * al.y, p.z * al.z, p.w * al.w);
        *(float4*)&X[((size_t)pair * NPTS + n0 + dn) * DIM + dq] = x;
        S[dq][dn] = x.x; S[dq + 1][dn] = x.y; S[dq + 2][dn] = x.z; S[dq + 3][dn] = x.w;
    }
    __syncthreads();
    if (tid < 64) {
        float s = 0.f;
#pragma unroll
        for (int d = 0; d < DIM; d++) { float v = S[d][tid]; s += v * v; }
        sqX[pair * NPTS + n0 + tid] = s;
        deg[pair * NPTS + n0 + tid] = 0.0f;
    }
    if (tid < 64) {
        int h = tid >> 5, d = tid & 31;   // pool group 0: sum X over two 32-row halves
        float s = 0.f;
#pragma unroll
        for (int k = 0; k < 32; k++) s += S[d][h * 32 + k];
        poolP[(((size_t)0 * NPAIR + pair) * 32 + 2 * blockIdx.x + h) * 32 + d] = s;
    }
    for (int idx = tid; idx < DIM * 4; idx += 256) {
        int row = idx >> 2, nq = (idx & 3) * 16;
        ushort8v hv[2], lv[2];
#pragma unroll
        for (int i = 0; i < 16; i++) {
            float v = S[row][nq + i];
            u16 hb = bf16_rne(v);
            hv[i >> 3][i & 7] = hb;
            lv[i >> 3][i & 7] = bf16_rne(v - bf16_to_f32(hb));
        }
        size_t o = ((size_t)pair * DIM + row) * NPTS + n0 + nq;
        *(ushort8v*)(hiT + o) = hv[0]; *(ushort8v*)(hiT + o + 8) = hv[1];
        *(ushort8v*)(loT + o) = lv[0]; *(ushort8v*)(loT + o + 8) = lv[1];
    }
}

// ============ single-pass W: W u8 (q = round(255*W)); deg = sum of quantized q ============
// grid 1024 blocks flat: xcd = b&7 -> pair = xcd*2 + (loc&1); block 256
__global__ __launch_bounds__(256, 4) void W_kernel(const float* __restrict__ X,
                                                   const float* __restrict__ sqX,
                                                   const float* __restrict__ sigp,
                                                   float* __restrict__ deg,
                                                   u8* __restrict__ W8) {
    int bid = blockIdx.x;
    int xcd = bid & 7, loc = bid >> 3;          // loc 0..127
    int pair = xcd * 2 + (loc & 1);
    int j0 = ((loc >> 1) & 3) * 256;
    int i0 = (loc >> 3) * 64;
    float rsig = -1.0f / (*sigp);
    const float* Xp = X + (size_t)pair * NPTS * DIM;

    __shared__ float XiT[DIM][68];
    __shared__ float XjT[DIM][68];
    __shared__ float sqjS[64];

    int tid = threadIdx.x;
    int cx = tid & 15, ry = tid >> 4;

    {
        int r = tid & 63, dgb = (tid >> 6) * 4;
#pragma unroll
        for (int p = 0; p < 2; p++) {
            int dg = dgb + p * 16;
            float4 v = *(const float4*)&Xp[(size_t)(i0 + r) * DIM + dg];
            XiT[dg][r] = v.x; XiT[dg + 1][r] = v.y; XiT[dg + 2][r] = v.z; XiT[dg + 3][r] = v.w;
        }
    }
    float sqi[4];
#pragma unroll
    for (int a = 0; a < 4; a++) sqi[a] = sqX[pair * NPTS + i0 + ry * 4 + a];

    float rs[4] = {0.f, 0.f, 0.f, 0.f};
#pragma unroll 1
    for (int jt = 0; jt < 256; jt += 64) {
        __syncthreads();
        {
            int r = tid & 63, dgb = (tid >> 6) * 4;
#pragma unroll
            for (int p = 0; p < 2; p++) {
                int dg = dgb + p * 16;
                float4 v = *(const float4*)&Xp[(size_t)(j0 + jt + r) * DIM + dg];
                XjT[dg][r] = v.x; XjT[dg + 1][r] = v.y; XjT[dg + 2][r] = v.z; XjT[dg + 3][r] = v.w;
            }
        }
        if (tid < 64) sqjS[tid] = sqX[pair * NPTS + j0 + jt + tid];
        __syncthreads();

        float dot[4][4] = {};
#pragma unroll
        for (int d = 0; d < DIM; d++) {
            float4 a = *(const float4*)&XiT[d][ry * 4];
            float4 b = *(const float4*)&XjT[d][cx * 4];
            dot[0][0] += a.x * b.x; dot[0][1] += a.x * b.y; dot[0][2] += a.x * b.z; dot[0][3] += a.x * b.w;
            dot[1][0] += a.y * b.x; dot[1][1] += a.y * b.y; dot[1][2] += a.y * b.z; dot[1][3] += a.y * b.w;
            dot[2][0] += a.z * b.x; dot[2][1] += a.z * b.y; dot[2][2] += a.z * b.z; dot[2][3] += a.z * b.w;
            dot[3][0] += a.w * b.x; dot[3][1] += a.w * b.y; dot[3][2] += a.w * b.z; dot[3][3] += a.w * b.w;
        }
#pragma unroll
        for (int a = 0; a < 4; a++) {
            int i = i0 + ry * 4 + a;
            int jb = j0 + jt + cx * 4;
            unsigned qw = 0;
#pragma unroll
            for (int bb = 0; bb < 4; bb++) {
                float Dm = sqi[a] + sqjS[cx * 4 + bb] - 2.0f * dot[a][bb];
                float K = __expf(Dm * rsig);
                float Wv = (K >= 0.5f) ? K : 0.0f;
                unsigned q = (unsigned)fmaf(Wv, 255.0f, 0.5f);   // 0 or 128..255
                rs[a] += (float)q;                                // deg tracks the QUANTIZED sum
                qw |= q << (8 * bb);
            }
            *(unsigned*)(W8 + ((size_t)pair * NPTS + i) * NPTS + jb) = qw;
        }
    }
#pragma unroll
    for (int a = 0; a < 4; a++) {
        float s = rs[a];
        s += __shfl_xor(s, 1); s += __shfl_xor(s, 2);
        s += __shfl_xor(s, 4); s += __shfl_xor(s, 8);
        if (cx == 0) atomicAdd(&deg[pair * NPTS + i0 + ry * 4 + a], s);
    }
}

// ============ generic fused apply: O = 0.5*Y + (0.5/deg)*(Wq@Y); 32-row tiles, k-split=8 ============
// grid 512 blocks flat (pair = (b&7)*2 + ((b>>3)&1), rowtile = b>>4), block 512
template <int DC>
__global__ __launch_bounds__(512, 4) void apply_fused(const u8* __restrict__ W8,
                                                      const u16* __restrict__ Yhi,
                                                      const u16* __restrict__ Ylo,
                                                      const float* __restrict__ deg,
                                                      const float* __restrict__ prevF,
                                                      int prevStride, int prevOff,
                                                      float* __restrict__ dstF,
                                                      int dstStride, int dstOff,
                                                      float* __restrict__ sliceF,  // cols 32..63 -> stride 32
                                                      u16* __restrict__ hiT, u16* __restrict__ loT,
                                                      int tC0, int tCN) {
    constexpr int NT = DC / 16;
    constexpr int SP = DC + 4;
    __shared__ float S[4][32][SP];
    __shared__ float rdegS[32];
    int bid = blockIdx.x;
    int pair = (bid & 7) * 2 + ((bid >> 3) & 1);
    int r0 = (bid >> 4) * 32;
    int tid = threadIdx.x;
    int wv = tid >> 6, lane = tid & 63;
    int m = lane & 15, quad = lane >> 4;
    int kb = wv * 128;

    if (tid < 32) rdegS[tid] = 0.5f / deg[pair * NPTS + r0 + tid];

    size_t aoff = ((size_t)pair * NPTS + r0 + m) * NPTS + kb + quad * 8;
    size_t boff = ((size_t)pair * DC + m) * NPTS + kb + quad * 8;

    f32x4 acc[2][NT];
#pragma unroll
    for (int mt = 0; mt < 2; mt++)
#pragma unroll
        for (int nt = 0; nt < NT; nt++)
#pragma unroll
            for (int i = 0; i < 4; i++) acc[mt][nt][i] = 0.0f;

#pragma unroll 2
    for (int c = 0; c < 4; c++) {
        int ko = c * 32;
        uint2 a0q = *(const uint2*)(W8 + aoff + ko);
        uint2 a1q = *(const uint2*)(W8 + aoff + 16 * NPTS + ko);
        short8 a0h = unpack_w8(a0q.x, a0q.y);
        short8 a1h = unpack_w8(a1q.x, a1q.y);
#pragma unroll
        for (int nt = 0; nt < NT; nt++) {
            short8 bh = *(const short8*)(Yhi + boff + (size_t)nt * 16 * NPTS + ko);
            short8 bl = *(const short8*)(Ylo + boff + (size_t)nt * 16 * NPTS + ko);
            acc[0][nt] = __builtin_amdgcn_mfma_f32_16x16x32_bf16(a0h, bh, acc[0][nt], 0, 0, 0);
            acc[0][nt] = __builtin_amdgcn_mfma_f32_16x16x32_bf16(a0h, bl, acc[0][nt], 0, 0, 0);
            acc[1][nt] = __builtin_amdgcn_mfma_f32_16x16x32_bf16(a1h, bh, acc[1][nt], 0, 0, 0);
            acc[1][nt] = __builtin_amdgcn_mfma_f32_16x16x32_bf16(a1h, bl, acc[1][nt], 0, 0, 0);
        }
    }

    if (wv < 4) {
#pragma unroll
        for (int mt = 0; mt < 2; mt++)
#pragma unroll
            for (int nt = 0; nt < NT; nt++)
#pragma unroll
                for (int i = 0; i < 4; i++)
                    S[wv][mt * 16 + quad * 4 + i][nt * 16 + m] = acc[mt][nt][i];
    }
    __syncthreads();
    if (wv >= 4) {
#pragma unroll
        for (int mt = 0; mt < 2; mt++)
#pragma unroll
            for (int nt = 0; nt < NT; nt++)
#pragma unroll
                for (int i = 0; i < 4; i++)
                    S[wv - 4][mt * 16 + quad * 4 + i][nt * 16 + m] += acc[mt][nt][i];
    }
    __syncthreads();

    constexpr int E2 = 32 * DC / 4;
    for (int e = tid; e < E2; e += 512) {
        int e4 = e * 4;
        int n = e4 / DC, d = e4 % DC;
        float4 s0 = *(const float4*)&S[0][n][d];
        float4 s1 = *(const float4*)&S[1][n][d];
        float4 s2 = *(const float4*)&S[2][n][d];
        float4 s3 = *(const float4*)&S[3][n][d];
        float4 pv = *(const float4*)&prevF[((size_t)pair * NPTS + r0 + n) * prevStride + prevOff + d];
        float r = rdegS[n];
        float4 o = make_float4(0.5f * pv.x + r * (s0.x + s1.x + s2.x + s3.x),
                               0.5f * pv.y + r * (s0.y + s1.y + s2.y + s3.y),
                               0.5f * pv.z + r * (s0.z + s1.z + s2.z + s3.z),
                               0.5f * pv.w + r * (s0.w + s1.w + s2.w + s3.w));
        *(float4*)&dstF[((size_t)pair * NPTS + r0 + n) * dstStride + dstOff + d] = o;
        if (sliceF && d >= 32 && d < 64)
            *(float4*)&sliceF[((size_t)pair * NPTS + r0 + n) * 32 + (d - 32)] = o;
        *(float4*)&S[0][n][d] = o;
    }
    __syncthreads();

    if (hiT) {
        for (int e = tid; e < tCN * 4; e += 512) {
            int row = e >> 2, nq = (e & 3) * 8;
            ushort8v hv, lv;
#pragma unroll
            for (int j = 0; j < 8; j++) {
                float v = S[0][nq + j][tC0 + row];
                u16 hb = bf16_rne(v);
                hv[j] = hb;
                lv[j] = bf16_rne(v - bf16_to_f32(hb));
            }
            size_t o = ((size_t)pair * tCN + row) * NPTS + r0 + nq;
            *(ushort8v*)(hiT + o) = hv;
            *(ushort8v*)(loT + o) = lv;
        }
    }
}

// ============ fat apply A4: DC=32 apply -> M0 cols 0..31, + build M0 cols 32..95,
//              + full 96-row M0T hi/lo, + pool partials for groups 1,2 ============
__global__ __launch_bounds__(512, 4) void apply_fused_m0(const u8* __restrict__ W8,
                                                         const u16* __restrict__ Yhi,
                                                         const u16* __restrict__ Ylo,
                                                         const float* __restrict__ deg,
                                                         const float* __restrict__ prevF,   // A3, stride 32
                                                         const float* __restrict__ A1,
                                                         const float* __restrict__ A2,
                                                         float* __restrict__ M0,            // stride 96
                                                         u16* __restrict__ hiT, u16* __restrict__ loT,  // T96a
                                                         float* __restrict__ poolP) {
    constexpr int DC = 32, NT = 2, SP = 36;
    __shared__ float S[4][32][SP];
    __shared__ float rdegS[32];
    __shared__ float SB[96][33];
    int bid = blockIdx.x;
    int pair = (bid & 7) * 2 + ((bid >> 3) & 1);
    int r0 = (bid >> 4) * 32;
    int rt = bid >> 4;
    int tid = threadIdx.x;
    int wv = tid >> 6, lane = tid & 63;
    int m = lane & 15, quad = lane >> 4;
    int kb = wv * 128;

    if (tid < 32) rdegS[tid] = 0.5f / deg[pair * NPTS + r0 + tid];

    size_t aoff = ((size_t)pair * NPTS + r0 + m) * NPTS + kb + quad * 8;
    size_t boff = ((size_t)pair * DC + m) * NPTS + kb + quad * 8;

    f32x4 acc[2][NT];
#pragma unroll
    for (int mt = 0; mt < 2; mt++)
#pragma unroll
        for (int nt = 0; nt < NT; nt++)
#pragma unroll
            for (int i = 0; i < 4; i++) acc[mt][nt][i] = 0.0f;

#pragma unroll 2
    for (int c = 0; c < 4; c++) {
        int ko = c * 32;
        uint2 a0q = *(const uint2*)(W8 + aoff + ko);
        uint2 a1q = *(const uint2*)(W8 + aoff + 16 * NPTS + ko);
        short8 a0h = unpack_w8(a0q.x, a0q.y);
        short8 a1h = unpack_w8(a1q.x, a1q.y);
#pragma unroll
        for (int nt = 0; nt < NT; nt++) {
            short8 bh = *(const short8*)(Yhi + boff + (size_t)nt * 16 * NPTS + ko);
            short8 bl = *(const short8*)(Ylo + boff + (size_t)nt * 16 * NPTS + ko);
            acc[0][nt] = __builtin_amdgcn_mfma_f32_16x16x32_bf16(a0h, bh, acc[0][nt], 0, 0, 0);
            acc[0][nt] = __builtin_amdgcn_mfma_f32_16x16x32_bf16(a0h, bl, acc[0][nt], 0, 0, 0);
            acc[1][nt] = __builtin_amdgcn_mfma_f32_16x16x32_bf16(a1h, bh, acc[1][nt], 0, 0, 0);
            acc[1][nt] = __builtin_amdgcn_mfma_f32_16x16x32_bf16(a1h, bl, acc[1][nt], 0, 0, 0);
        }
    }

    if (wv < 4) {
#pragma unroll
        for (int mt = 0; mt < 2; mt++)
#pragma unroll
            for (int nt = 0; nt < NT; nt++)
#pragma unroll
                for (int i = 0; i < 4; i++)
                    S[wv][mt * 16 + quad * 4 + i][nt * 16 + m] = acc[mt][nt][i];
    }
    __syncthreads();
    if (wv >= 4) {
#pragma unroll
        for (int mt = 0; mt < 2; mt++)
#pragma unroll
            for (int nt = 0; nt < NT; nt++)
#pragma unroll
                for (int i = 0; i < 4; i++)
                    S[wv - 4][mt * 16 + quad * 4 + i][nt * 16 + m] += acc[mt][nt][i];
    }
    __syncthreads();

    // phase 2: T4 rows -> M0 cols 0..31 + stash in S[0]
    for (int e = tid; e < 256; e += 512) {
        int e4 = e * 4;
        int n = e4 / DC, d = e4 % DC;
        float4 s0 = *(const float4*)&S[0][n][d];
        float4 s1 = *(const float4*)&S[1][n][d];
        float4 s2 = *(const float4*)&S[2][n][d];
        float4 s3 = *(const float4*)&S[3][n][d];
        float4 pv = *(const float4*)&prevF[((size_t)pair * NPTS + r0 + n) * 32 + d];
        float r = rdegS[n];
        float4 o = make_float4(0.5f * pv.x + r * (s0.x + s1.x + s2.x + s3.x),
                               0.5f * pv.y + r * (s0.y + s1.y + s2.y + s3.y),
                               0.5f * pv.z + r * (s0.z + s1.z + s2.z + s3.z),
                               0.5f * pv.w + r * (s0.w + s1.w + s2.w + s3.w));
        *(float4*)&M0[((size_t)pair * NPTS + r0 + n) * 96 + d] = o;
        *(float4*)&S[0][n][d] = o;
    }
    __syncthreads();

    // build-M0 tail: f0 = |A1-A2|, f1 = |A2-T4|; M0 cols 32..95; SB[96][n] transposed
    if (tid < 256) {
        int dn = tid >> 3, dq = (tid & 7) * 4;
        size_t pn = (size_t)pair * NPTS + r0 + dn;
        float4 a1 = *(const float4*)&A1[pn * 32 + dq];
        float4 a2 = *(const float4*)&A2[pn * 32 + dq];
        float4 t4 = *(const float4*)&S[0][dn][dq];
        float4 f0 = make_float4(fabsf(a1.x - a2.x), fabsf(a1.y - a2.y), fabsf(a1.z - a2.z), fabsf(a1.w - a2.w));
        float4 f1 = make_float4(fabsf(a2.x - t4.x), fabsf(a2.y - t4.y), fabsf(a2.z - t4.z), fabsf(a2.w - t4.w));
        *(float4*)&M0[pn * 96 + 32 + dq] = f0;
        *(float4*)&M0[pn * 96 + 64 + dq] = f1;
        SB[dq][dn] = t4.x; SB[dq + 1][dn] = t4.y; SB[dq + 2][dn] = t4.z; SB[dq + 3][dn] = t4.w;
        SB[32 + dq][dn] = f0.x; SB[33 + dq][dn] = f0.y; SB[34 + dq][dn] = f0.z; SB[35 + dq][dn] = f0.w;
        SB[64 + dq][dn] = f1.x; SB[65 + dq][dn] = f1.y; SB[66 + dq][dn] = f1.z; SB[67 + dq][dn] = f1.w;
    }
    __syncthreads();

    // pool partials groups 1 (f0) and 2 (f1): column sums over this block's 32 rows
    if (tid < 64) {
        int gg = tid >> 5, d = tid & 31;
        float s = 0.f;
#pragma unroll
        for (int k = 0; k < 32; k++) s += SB[32 + gg * 32 + d][k];
        poolP[(((size_t)(1 + gg) * NPAIR + pair) * 32 + rt) * 32 + d] = s;
    }

    // phase 3: transposed bf16 hi/lo of all 96 M0 rows for the M-chain
    for (int e = tid; e < 96 * 4; e += 512) {
        int row = e >> 2, nq = (e & 3) * 8;
        ushort8v hv, lv;
#pragma unroll
        for (int j = 0; j < 8; j++) {
            float v = SB[row][nq + j];
            u16 hb = bf16_rne(v);
            hv[j] = hb;
            lv[j] = bf16_rne(v - bf16_to_f32(hb));
        }
        size_t o = ((size_t)pair * 96 + row) * NPTS + r0 + nq;
        *(ushort8v*)(hiT + o) = hv;
        *(ushort8v*)(loT + o) = lv;
    }
}

// ============ fat apply N4: DC=64 apply -> Z8, + pool partials for groups 3..6 ============
__global__ __launch_bounds__(512, 4) void apply_fused_pool(const u8* __restrict__ W8,
                                                           const u16* __restrict__ Yhi,
                                                           const u16* __restrict__ Ylo,
                                                           const float* __restrict__ deg,
                                                           const float* __restrict__ prevF,  // F96a, stride 64
                                                           float* __restrict__ Z8,           // stride 64
                                                           const float* __restrict__ M0,
                                                           const float* __restrict__ M2p,
                                                           const float* __restrict__ M4f,
                                                           float* __restrict__ poolP) {
    constexpr int DC = 64, NT = 4, SP = 68;
    __shared__ float S[4][32][SP];
    __shared__ float rdegS[32];
    __shared__ float PP[4][2][32];
    int bid = blockIdx.x;
    int pair = (bid & 7) * 2 + ((bid >> 3) & 1);
    int r0 = (bid >> 4) * 32;
    int rt = bid >> 4;
    int tid = threadIdx.x;
    int wv = tid >> 6, lane = tid & 63;
    int m = lane & 15, quad = lane >> 4;
    int kb = wv * 128;

    if (tid < 32) rdegS[tid] = 0.5f / deg[pair * NPTS + r0 + tid];

    size_t aoff = ((size_t)pair * NPTS + r0 + m) * NPTS + kb + quad * 8;
    size_t boff = ((size_t)pair * DC + m) * NPTS + kb + quad * 8;

    f32x4 acc[2][NT];
#pragma unroll
    for (int mt = 0; mt < 2; mt++)
#pragma unroll
        for (int nt = 0; nt < NT; nt++)
#pragma unroll
            for (int i = 0; i < 4; i++) acc[mt][nt][i] = 0.0f;

#pragma unroll 2
    for (int c = 0; c < 4; c++) {
        int ko = c * 32;
        uint2 a0q = *(const uint2*)(W8 + aoff + ko);
        uint2 a1q = *(const uint2*)(W8 + aoff + 16 * NPTS + ko);
        short8 a0h = unpack_w8(a0q.x, a0q.y);
        short8 a1h = unpack_w8(a1q.x, a1q.y);
#pragma unroll
        for (int nt = 0; nt < NT; nt++) {
            short8 bh = *(const short8*)(Yhi + boff + (size_t)nt * 16 * NPTS + ko);
            short8 bl = *(const short8*)(Ylo + boff + (size_t)nt * 16 * NPTS + ko);
            acc[0][nt] = __builtin_amdgcn_mfma_f32_16x16x32_bf16(a0h, bh, acc[0][nt], 0, 0, 0);
            acc[0][nt] = __builtin_amdgcn_mfma_f32_16x16x32_bf16(a0h, bl, acc[0][nt], 0, 0, 0);
            acc[1][nt] = __builtin_amdgcn_mfma_f32_16x16x32_bf16(a1h, bh, acc[1][nt], 0, 0, 0);
            acc[1][nt] = __builtin_amdgcn_mfma_f32_16x16x32_bf16(a1h, bl, acc[1][nt], 0, 0, 0);
        }
    }

    if (wv < 4) {
#pragma unroll
        for (int mt = 0; mt < 2; mt++)
#pragma unroll
            for (int nt = 0; nt < NT; nt++)
#pragma unroll
                for (int i = 0; i < 4; i++)
                    S[wv][mt * 16 + quad * 4 + i][nt * 16 + m] = acc[mt][nt][i];
    }
    __syncthreads();
    if (wv >= 4) {
#pragma unroll
        for (int mt = 0; mt < 2; mt++)
#pragma unroll
            for (int nt = 0; nt < NT; nt++)
#pragma unroll
                for (int i = 0; i < 4; i++)
                    S[wv - 4][mt * 16 + quad * 4 + i][nt * 16 + m] += acc[mt][nt][i];
    }
    __syncthreads();

    for (int e = tid; e < 512; e += 512) {
        int e4 = e * 4;
        int n = e4 / DC, d = e4 % DC;
        float4 s0 = *(const float4*)&S[0][n][d];
        float4 s1 = *(const float4*)&S[1][n][d];
        float4 s2 = *(const float4*)&S[2][n][d];
        float4 s3 = *(const float4*)&S[3][n][d];
        float4 pv = *(const float4*)&prevF[((size_t)pair * NPTS + r0 + n) * 64 + d];
        float r = rdegS[n];
        float4 o = make_float4(0.5f * pv.x + r * (s0.x + s1.x + s2.x + s3.x),
                               0.5f * pv.y + r * (s0.y + s1.y + s2.y + s3.y),
                               0.5f * pv.z + r * (s0.z + s1.z + s2.z + s3.z),
                               0.5f * pv.w + r * (s0.w + s1.w + s2.w + s3.w));
        *(float4*)&Z8[((size_t)pair * NPTS + r0 + n) * 64 + d] = o;
        *(float4*)&S[0][n][d] = o;
    }
    __syncthreads();

    // pool partials groups 3..6 (Z8 read from S[0], rest from global rows r0..r0+32)
    if (tid < 256) {
        int gsel = tid >> 6, h = (tid >> 5) & 1, d = tid & 31;
        float s = 0.f;
#pragma unroll 4
        for (int k = 0; k < 16; k++) {
            int n = h * 16 + k;
            size_t pn = (size_t)pair * NPTS + r0 + n;
            float v;
            switch (gsel) {
                case 0: v = fabsf(M0[pn * 96 + d] - M4f[pn * 96 + d]); break;
                case 1: v = fabsf(M2p[pn * 32 + d] - M4f[pn * 96 + 32 + d]); break;
                case 2: v = fabsf(M4f[pn * 96 + 32 + d] - S[0][n][d]); break;
                default: v = fabsf(M4f[pn * 96 + 64 + d] - S[0][n][32 + d]); break;
            }
            s += v;
        }
        PP[gsel][h][d] = s;
    }
    __syncthreads();
    if (tid < 128) {
        int gsel = tid >> 5, d = tid & 31;
        poolP[(((size_t)(3 + gsel) * NPAIR + pair) * 32 + rt) * 32 + d] = PP[gsel][0][d] + PP[gsel][1][d];
    }
}

// ============ pool final: grid (NPAIR), block 256; reduce 32 rowtile partials ============
__global__ __launch_bounds__(256) void pool_final(const float* __restrict__ partial,
                                                  float* __restrict__ out) {
    int pair = blockIdx.x;
    int t = threadIdx.x;
    if (t < 224) {
        int g = t >> 5, d = t & 31;
        float s = 0.0f;
#pragma unroll 8
        for (int r = 0; r < 32; r++)
            s += partial[(((size_t)g * NPAIR + pair) * 32 + r) * 32 + d];
        out[(size_t)pair * 224 + t] = s * (1.0f / 1024.0f);
    }
}

extern "C" void kernel_launch(void* const* d_in, const int* in_sizes, int n_in,
                              void* d_out, int out_size, void* d_ws, size_t ws_size,
                              hipStream_t stream) {
    const float* pc     = (const float*)d_in[0];
    const float* alphas = (const float*)d_in[1];
    const float* sigp   = (const float*)d_in[2];
    float* out = (float*)d_out;
    float* ws = (float*)d_ws;

    // ---- workspace layout ----
    float* X    = ws;                         // 524288
    float* sqX  = X + 524288;                 // 16384
    float* deg  = sqX + 16384;                // 16384
    u8* W8 = (u8*)(deg + 16384);              // 16777216 u8
    float* A1   = (float*)(W8 + 16777216);    // 524288
    float* A2   = A1 + 524288;                // 524288
    u16* T32a_h = (u16*)(A2 + 524288);        // 524288 u16 each
    u16* T32a_l = T32a_h + 524288;
    u16* T32b_h = T32a_l + 524288;
    u16* T32b_l = T32b_h + 524288;
    float* F96b = A1;                         // overlay (A1,A2,T32a_h/l dead by then)
    float* M0   = (float*)(T32b_l + 524288);  // 1572864
    float* M2p  = M0 + 1572864;               // 524288
    float* M4f  = M2p + 524288;               // 1572864
    float* Z8   = M4f + 1572864;              // 1048576
    float* F96a = Z8 + 1048576;               // 1572864  (also A3 overlay before M-chain)
    float* A3   = F96a;
    u16* T96a_h = (u16*)(F96a + 1572864);     // 1572864 u16 each
    u16* T96a_l = T96a_h + 1572864;
    u16* T96b_h = T96a_l + 1572864;
    u16* T96b_l = T96b_h + 1572864;
    u16* T64a_h = T96a_h;
    u16* T64a_l = T96a_l;
    u16* T64b_h = T96b_h;
    u16* T64b_l = T96b_l;
    float* poolP = (float*)(T96b_l + 1572864); // 7*16*32*32 = 114688 floats

    dim3 b256(256), b512(512);

    build_X<<<dim3(16, NPAIR), b256, 0, stream>>>(pc, alphas, X, sqX, deg, T32a_h, T32a_l, poolP);
    W_kernel<<<dim3(1024), b256, 0, stream>>>(X, sqX, sigp, deg, W8);

    // ---- A-chain (D=32) ----
    apply_fused<32><<<dim3(512), b512, 0, stream>>>(W8, T32a_h, T32a_l, deg,
                                             X, 32, 0, A1, 32, 0, nullptr, T32b_h, T32b_l, 0, 32);
    apply_fused<32><<<dim3(512), b512, 0, stream>>>(W8, T32b_h, T32b_l, deg,
                                             A1, 32, 0, A2, 32, 0, nullptr, T32a_h, T32a_l, 0, 32);
    apply_fused<32><<<dim3(512), b512, 0, stream>>>(W8, T32a_h, T32a_l, deg,
                                             A2, 32, 0, A3, 32, 0, nullptr, T32b_h, T32b_l, 0, 32);
    apply_fused_m0<<<dim3(512), b512, 0, stream>>>(W8, T32b_h, T32b_l, deg,
                                             A3, A1, A2, M0, T96a_h, T96a_l, poolP);

    // ---- M-chain (D=96) ----
    apply_fused<96><<<dim3(512), b512, 0, stream>>>(W8, T96a_h, T96a_l, deg,
                                             M0, 96, 0, F96a, 96, 0, nullptr, T96b_h, T96b_l, 0, 96);
    apply_fused<96><<<dim3(512), b512, 0, stream>>>(W8, T96b_h, T96b_l, deg,
                                             F96a, 96, 0, F96b, 96, 0, M2p, T96a_h, T96a_l, 0, 96);
    apply_fused<96><<<dim3(512), b512, 0, stream>>>(W8, T96a_h, T96a_l, deg,
                                             F96b, 96, 0, F96a, 96, 0, nullptr, T96b_h, T96b_l, 0, 96);
    apply_fused<96><<<dim3(512), b512, 0, stream>>>(W8, T96b_h, T96b_l, deg,
                                             F96a, 96, 0, M4f, 96, 0, nullptr, T64a_h, T64a_l, 32, 64);

    // ---- N-chain (D=64) ----
    apply_fused<64><<<dim3(512), b512, 0, stream>>>(W8, T64a_h, T64a_l, deg,
                                             M4f, 96, 32, F96a, 64, 0, nullptr, T64b_h, T64b_l, 0, 64);
    apply_fused<64><<<dim3(512), b512, 0, stream>>>(W8, T64b_h, T64b_l, deg,
                                             F96a, 64, 0, F96b, 64, 0, nullptr, T64a_h, T64a_l, 0, 64);
    apply_fused<64><<<dim3(512), b512, 0, stream>>>(W8, T64a_h, T64a_l, deg,
                                             F96b, 64, 0, F96a, 64, 0, nullptr, T64b_h, T64b_l, 0, 64);
    apply_fused_pool<<<dim3(512), b512, 0, stream>>>(W8, T64b_h, T64b_l, deg,
                                             F96a, Z8, M0, M2p, M4f, poolP);

    pool_final<<<dim3(NPAIR), b256, 0, stream>>>(poolP, out);
}

// Round 5
// 235.223 us; speedup vs baseline: 4.5779x; 1.5631x over previous
//
#include <hip/hip_runtime.h>
#include <math.h>

#define NPTS 1024
#define DIM 32
#define NPAIR 16   // B*NW

typedef __attribute__((ext_vector_type(8))) short short8;
typedef __attribute__((ext_vector_type(4))) float f32x4;
typedef __attribute__((ext_vector_type(8))) unsigned short ushort8v;
typedef unsigned short u16;
typedef unsigned char u8;

// ---------------- fragment-ordered layouts (MFMA-native) ----------------
// A-side (W8): fragment = 16 rows x 32 K u8. slot(lane) = quad*16 + m, lane holds 8 K-bytes.
//   addr = (((pair*64 + rowtile)*32 + ktile) << 9) + lane*8 + j          [bytes]
// B-side (T panels, u16): fragment = 16 features x 32 points (K).
//   addr = (((pair*NF + ftile)*32 + ktile) << 9) + lane*8 + j            [u16 units]
// Every wave k-loop load is then a contiguous 512B (A) / 1KB (B) block.

__device__ __forceinline__ u16 bf16_rne(float v) {
    unsigned u = __float_as_uint(v);
    return (u16)((u + 0x7fffu + ((u >> 16) & 1u)) >> 16);
}
__device__ __forceinline__ float bf16_to_f32(u16 b) {
    return __uint_as_float(((unsigned)b) << 16);
}

// u8 W (0..255) -> bf16 short8. Integers <=255 are exact in bf16.
__device__ __forceinline__ short8 unpack_w8(unsigned lo, unsigned hi) {
    short8 r;
#pragma unroll
    for (int j = 0; j < 4; j++) {
        float f0 = (float)((lo >> (8 * j)) & 0xffu);
        float f1 = (float)((hi >> (8 * j)) & 0xffu);
        r[j]     = (short)(__float_as_uint(f0) >> 16);
        r[j + 4] = (short)(__float_as_uint(f1) >> 16);
    }
    return r;
}

// ============ build_X: X + sqX + XT hi/lo (fragment order) + zero deg + pool group-0 ============
// grid (16 ntiles, NPAIR), block 256
__global__ __launch_bounds__(256) void build_X(const float* __restrict__ pc,
                                               const float* __restrict__ alphas,
                                               float* __restrict__ X,
                                               float* __restrict__ sqX,
                                               float* __restrict__ deg,
                                               u16* __restrict__ hiT,
                                               u16* __restrict__ loT,
                                               float* __restrict__ poolP) {
    __shared__ float S[DIM][68];
    int pair = blockIdx.y, n0 = blockIdx.x * 64, tid = threadIdx.x;
    int b = pair >> 2, w = pair & 3;
    for (int e = tid; e < 512; e += 256) {
        int e4 = e * 4;
        int dn = e4 >> 5, dq = e4 & 31;
        float4 p = *(const float4*)&pc[((size_t)b * NPTS + n0 + dn) * DIM + dq];
        float4 al = *(const float4*)&alphas[w * DIM + dq];
        float4 x = make_float4(p.x * al.x, p.y * al.y, p.z * al.z, p.w * al.w);
        *(float4*)&X[((size_t)pair * NPTS + n0 + dn) * DIM + dq] = x;
        S[dq][dn] = x.x; S[dq + 1][dn] = x.y; S[dq + 2][dn] = x.z; S[dq + 3][dn] = x.w;
    }
    __syncthreads();
    if (tid < 64) {
        float s = 0.f;
#pragma unroll
        for (int d = 0; d < DIM; d++) { float v = S[d][tid]; s += v * v; }
        sqX[pair * NPTS + n0 + tid] = s;
        deg[pair * NPTS + n0 + tid] = 0.0f;
    }
    if (tid < 64) {
        int h = tid >> 5, d = tid & 31;   // pool group 0
        float s = 0.f;
#pragma unroll
        for (int k = 0; k < 32; k++) s += S[d][h * 32 + k];
        poolP[(((size_t)0 * NPAIR + pair) * 32 + 2 * blockIdx.x + h) * 32 + d] = s;
    }
    for (int idx = tid; idx < DIM * 4; idx += 256) {
        int row = idx >> 2, nq = (idx & 3) * 16;
        ushort8v hv[2], lv[2];
#pragma unroll
        for (int i = 0; i < 16; i++) {
            float v = S[row][nq + i];
            u16 hb = bf16_rne(v);
            hv[i >> 3][i & 7] = hb;
            lv[i >> 3][i & 7] = bf16_rne(v - bf16_to_f32(hb));
        }
        // fragment-order write: points c0..c0+15 span quads q0, q0+1 of ktile kt
        int c0 = n0 + nq;
        int kt = c0 >> 5;
        int q0 = (c0 >> 3) & 3;        // 0 or 2
        int mm = row & 15;
        size_t base = ((((size_t)pair * 2 + (row >> 4)) * 32 + kt) << 9);   // NF=2
        *(ushort8v*)(hiT + base + (size_t)(q0 * 16 + mm) * 8)       = hv[0];
        *(ushort8v*)(hiT + base + (size_t)((q0 + 1) * 16 + mm) * 8) = hv[1];
        *(ushort8v*)(loT + base + (size_t)(q0 * 16 + mm) * 8)       = lv[0];
        *(ushort8v*)(loT + base + (size_t)((q0 + 1) * 16 + mm) * 8) = lv[1];
    }
}

// ============ W_kernel: W u8 fragment-order; deg = sum of quantized q ============
// grid 1024 blocks flat: xcd = b&7 -> pair = xcd*2 + (loc&1); block 256
__global__ __launch_bounds__(256, 4) void W_kernel(const float* __restrict__ X,
                                                   const float* __restrict__ sqX,
                                                   const float* __restrict__ sigp,
                                                   float* __restrict__ deg,
                                                   u8* __restrict__ W8) {
    int bid = blockIdx.x;
    int xcd = bid & 7, loc = bid >> 3;          // loc 0..127
    int pair = xcd * 2 + (loc & 1);
    int j0 = ((loc >> 1) & 3) * 256;
    int i0 = (loc >> 3) * 64;
    float rsig = -1.0f / (*sigp);
    const float* Xp = X + (size_t)pair * NPTS * DIM;

    __shared__ float XiT[DIM][68];
    __shared__ float XjT[DIM][68];
    __shared__ float sqjS[64];

    int tid = threadIdx.x;
    int cx = tid & 15, ry = tid >> 4;

    {
        int r = tid & 63, dgb = (tid >> 6) * 4;
#pragma unroll
        for (int p = 0; p < 2; p++) {
            int dg = dgb + p * 16;
            float4 v = *(const float4*)&Xp[(size_t)(i0 + r) * DIM + dg];
            XiT[dg][r] = v.x; XiT[dg + 1][r] = v.y; XiT[dg + 2][r] = v.z; XiT[dg + 3][r] = v.w;
        }
    }
    float sqi[4];
#pragma unroll
    for (int a = 0; a < 4; a++) sqi[a] = sqX[pair * NPTS + i0 + ry * 4 + a];

    float rs[4] = {0.f, 0.f, 0.f, 0.f};
#pragma unroll 1
    for (int jt = 0; jt < 256; jt += 64) {
        __syncthreads();
        {
            int r = tid & 63, dgb = (tid >> 6) * 4;
#pragma unroll
            for (int p = 0; p < 2; p++) {
                int dg = dgb + p * 16;
                float4 v = *(const float4*)&Xp[(size_t)(j0 + jt + r) * DIM + dg];
                XjT[dg][r] = v.x; XjT[dg + 1][r] = v.y; XjT[dg + 2][r] = v.z; XjT[dg + 3][r] = v.w;
            }
        }
        if (tid < 64) sqjS[tid] = sqX[pair * NPTS + j0 + jt + tid];
        __syncthreads();

        float dot[4][4] = {};
#pragma unroll
        for (int d = 0; d < DIM; d++) {
            float4 a = *(const float4*)&XiT[d][ry * 4];
            float4 b = *(const float4*)&XjT[d][cx * 4];
            dot[0][0] += a.x * b.x; dot[0][1] += a.x * b.y; dot[0][2] += a.x * b.z; dot[0][3] += a.x * b.w;
            dot[1][0] += a.y * b.x; dot[1][1] += a.y * b.y; dot[1][2] += a.y * b.z; dot[1][3] += a.y * b.w;
            dot[2][0] += a.z * b.x; dot[2][1] += a.z * b.y; dot[2][2] += a.z * b.z; dot[2][3] += a.z * b.w;
            dot[3][0] += a.w * b.x; dot[3][1] += a.w * b.y; dot[3][2] += a.w * b.z; dot[3][3] += a.w * b.w;
        }
#pragma unroll
        for (int a = 0; a < 4; a++) {
            int i = i0 + ry * 4 + a;
            int jb = j0 + jt + cx * 4;
            unsigned qw = 0;
#pragma unroll
            for (int bb = 0; bb < 4; bb++) {
                float Dm = sqi[a] + sqjS[cx * 4 + bb] - 2.0f * dot[a][bb];
                float K = __expf(Dm * rsig);
                float Wv = (K >= 0.5f) ? K : 0.0f;
                unsigned q = (unsigned)fmaf(Wv, 255.0f, 0.5f);   // 0 or 128..255
                rs[a] += (float)q;                                // deg tracks the QUANTIZED sum
                qw |= q << (8 * bb);
            }
            // fragment-order store: 4 K-bytes jb..jb+3 of row i
            int kt = jb >> 5;
            int quad = (jb >> 3) & 3;
            int jj = jb & 7;                     // 0 or 4
            size_t o = ((((size_t)pair * 64 + (i >> 4)) * 32 + kt) << 9)
                     + (size_t)(quad * 16 + (i & 15)) * 8 + jj;
            *(unsigned*)(W8 + o) = qw;
        }
    }
#pragma unroll
    for (int a = 0; a < 4; a++) {
        float s = rs[a];
        s += __shfl_xor(s, 1); s += __shfl_xor(s, 2);
        s += __shfl_xor(s, 4); s += __shfl_xor(s, 8);
        if (cx == 0) atomicAdd(&deg[pair * NPTS + i0 + ry * 4 + a], s);
    }
}

// ============ generic fused apply: O = 0.5*Y + (0.5/deg)*(Wq@Y); fragment loads ============
// grid 512 blocks flat (pair = (b&7)*2 + ((b>>3)&1), rowtile = b>>4), block 512
template <int DC>
__global__ __launch_bounds__(512, 4) void apply_fused(const u8* __restrict__ W8,
                                                      const u16* __restrict__ Yhi,
                                                      const u16* __restrict__ Ylo,
                                                      const float* __restrict__ deg,
                                                      const float* __restrict__ prevF,
                                                      int prevStride, int prevOff,
                                                      float* __restrict__ dstF,
                                                      int dstStride, int dstOff,
                                                      float* __restrict__ sliceF,  // cols 32..63 -> stride 32
                                                      u16* __restrict__ hiT, u16* __restrict__ loT,
                                                      int tC0, int tCN) {
    constexpr int NT = DC / 16;
    constexpr int SP = DC + 4;
    __shared__ float S[4][32][SP];
    __shared__ float rdegS[32];
    int bid = blockIdx.x;
    int pair = (bid & 7) * 2 + ((bid >> 3) & 1);
    int r0 = (bid >> 4) * 32;
    int tid = threadIdx.x;
    int wv = tid >> 6, lane = tid & 63;
    int m = lane & 15, quad = lane >> 4;

    if (tid < 32) rdegS[tid] = 0.5f / deg[pair * NPTS + r0 + tid];

    // fragment-order bases: wave wv covers ktiles wv*4 .. wv*4+3
    int rt0 = (bid >> 4) * 2;
    const u8*  Wb  = W8  + ((((size_t)pair * 64 + rt0) * 32 + wv * 4) << 9) + (size_t)lane * 8;
    const u16* Ybh = Yhi + (((size_t)pair * NT * 32 + wv * 4) << 9) + (size_t)lane * 8;
    const u16* Ybl = Ylo + (((size_t)pair * NT * 32 + wv * 4) << 9) + (size_t)lane * 8;

    f32x4 acc[2][NT];
#pragma unroll
    for (int mt = 0; mt < 2; mt++)
#pragma unroll
        for (int nt = 0; nt < NT; nt++)
#pragma unroll
            for (int i = 0; i < 4; i++) acc[mt][nt][i] = 0.0f;

#pragma unroll 2
    for (int c = 0; c < 4; c++) {
        uint2 a0q = *(const uint2*)(Wb + ((size_t)c << 9));
        uint2 a1q = *(const uint2*)(Wb + ((size_t)(32 + c) << 9));
        short8 a0h = unpack_w8(a0q.x, a0q.y);
        short8 a1h = unpack_w8(a1q.x, a1q.y);
#pragma unroll
        for (int nt = 0; nt < NT; nt++) {
            short8 bh = *(const short8*)(Ybh + ((size_t)(nt * 32 + c) << 9));
            short8 bl = *(const short8*)(Ybl + ((size_t)(nt * 32 + c) << 9));
            acc[0][nt] = __builtin_amdgcn_mfma_f32_16x16x32_bf16(a0h, bh, acc[0][nt], 0, 0, 0);
            acc[0][nt] = __builtin_amdgcn_mfma_f32_16x16x32_bf16(a0h, bl, acc[0][nt], 0, 0, 0);
            acc[1][nt] = __builtin_amdgcn_mfma_f32_16x16x32_bf16(a1h, bh, acc[1][nt], 0, 0, 0);
            acc[1][nt] = __builtin_amdgcn_mfma_f32_16x16x32_bf16(a1h, bl, acc[1][nt], 0, 0, 0);
        }
    }

    if (wv < 4) {
#pragma unroll
        for (int mt = 0; mt < 2; mt++)
#pragma unroll
            for (int nt = 0; nt < NT; nt++)
#pragma unroll
                for (int i = 0; i < 4; i++)
                    S[wv][mt * 16 + quad * 4 + i][nt * 16 + m] = acc[mt][nt][i];
    }
    __syncthreads();
    if (wv >= 4) {
#pragma unroll
        for (int mt = 0; mt < 2; mt++)
#pragma unroll
            for (int nt = 0; nt < NT; nt++)
#pragma unroll
                for (int i = 0; i < 4; i++)
                    S[wv - 4][mt * 16 + quad * 4 + i][nt * 16 + m] += acc[mt][nt][i];
    }
    __syncthreads();

    constexpr int E2 = 32 * DC / 4;
    for (int e = tid; e < E2; e += 512) {
        int e4 = e * 4;
        int n = e4 / DC, d = e4 % DC;
        float4 s0 = *(const float4*)&S[0][n][d];
        float4 s1 = *(const float4*)&S[1][n][d];
        float4 s2 = *(const float4*)&S[2][n][d];
        float4 s3 = *(const float4*)&S[3][n][d];
        float4 pv = *(const float4*)&prevF[((size_t)pair * NPTS + r0 + n) * prevStride + prevOff + d];
        float r = rdegS[n];
        float4 o = make_float4(0.5f * pv.x + r * (s0.x + s1.x + s2.x + s3.x),
                               0.5f * pv.y + r * (s0.y + s1.y + s2.y + s3.y),
                               0.5f * pv.z + r * (s0.z + s1.z + s2.z + s3.z),
                               0.5f * pv.w + r * (s0.w + s1.w + s2.w + s3.w));
        *(float4*)&dstF[((size_t)pair * NPTS + r0 + n) * dstStride + dstOff + d] = o;
        if (sliceF && d >= 32 && d < 64)
            *(float4*)&sliceF[((size_t)pair * NPTS + r0 + n) * 32 + (d - 32)] = o;
        *(float4*)&S[0][n][d] = o;
    }
    __syncthreads();

    if (hiT) {
        int NFo = tCN >> 4;
        for (int e = tid; e < tCN * 4; e += 512) {
            int row = e >> 2, nq = (e & 3) * 8;
            ushort8v hv, lv;
#pragma unroll
            for (int j = 0; j < 8; j++) {
                float v = S[0][nq + j][tC0 + row];
                u16 hb = bf16_rne(v);
                hv[j] = hb;
                lv[j] = bf16_rne(v - bf16_to_f32(hb));
            }
            int c0 = r0 + nq;
            size_t o = ((((size_t)pair * NFo + (row >> 4)) * 32 + (c0 >> 5)) << 9)
                     + (size_t)((((c0 >> 3) & 3) * 16 + (row & 15))) * 8;
            *(ushort8v*)(hiT + o) = hv;
            *(ushort8v*)(loT + o) = lv;
        }
    }
}

// ============ fat apply A4: DC=32 apply -> M0 cols 0..31, + build M0 cols 32..95,
//              + full 96-row M0T hi/lo (fragment order), + pool groups 1,2 ============
__global__ __launch_bounds__(512, 4) void apply_fused_m0(const u8* __restrict__ W8,
                                                         const u16* __restrict__ Yhi,
                                                         const u16* __restrict__ Ylo,
                                                         const float* __restrict__ deg,
                                                         const float* __restrict__ prevF,   // A3, stride 32
                                                         const float* __restrict__ A1,
                                                         const float* __restrict__ A2,
                                                         float* __restrict__ M0,            // stride 96
                                                         u16* __restrict__ hiT, u16* __restrict__ loT,  // T96a
                                                         float* __restrict__ poolP) {
    constexpr int DC = 32, NT = 2, SP = 36;
    __shared__ float S[4][32][SP];
    __shared__ float rdegS[32];
    __shared__ float SB[96][33];
    int bid = blockIdx.x;
    int pair = (bid & 7) * 2 + ((bid >> 3) & 1);
    int r0 = (bid >> 4) * 32;
    int rt = bid >> 4;
    int tid = threadIdx.x;
    int wv = tid >> 6, lane = tid & 63;
    int m = lane & 15, quad = lane >> 4;

    if (tid < 32) rdegS[tid] = 0.5f / deg[pair * NPTS + r0 + tid];

    int rt0 = rt * 2;
    const u8*  Wb  = W8  + ((((size_t)pair * 64 + rt0) * 32 + wv * 4) << 9) + (size_t)lane * 8;
    const u16* Ybh = Yhi + (((size_t)pair * NT * 32 + wv * 4) << 9) + (size_t)lane * 8;
    const u16* Ybl = Ylo + (((size_t)pair * NT * 32 + wv * 4) << 9) + (size_t)lane * 8;

    f32x4 acc[2][NT];
#pragma unroll
    for (int mt = 0; mt < 2; mt++)
#pragma unroll
        for (int nt = 0; nt < NT; nt++)
#pragma unroll
            for (int i = 0; i < 4; i++) acc[mt][nt][i] = 0.0f;

#pragma unroll 2
    for (int c = 0; c < 4; c++) {
        uint2 a0q = *(const uint2*)(Wb + ((size_t)c << 9));
        uint2 a1q = *(const uint2*)(Wb + ((size_t)(32 + c) << 9));
        short8 a0h = unpack_w8(a0q.x, a0q.y);
        short8 a1h = unpack_w8(a1q.x, a1q.y);
#pragma unroll
        for (int nt = 0; nt < NT; nt++) {
            short8 bh = *(const short8*)(Ybh + ((size_t)(nt * 32 + c) << 9));
            short8 bl = *(const short8*)(Ybl + ((size_t)(nt * 32 + c) << 9));
            acc[0][nt] = __builtin_amdgcn_mfma_f32_16x16x32_bf16(a0h, bh, acc[0][nt], 0, 0, 0);
            acc[0][nt] = __builtin_amdgcn_mfma_f32_16x16x32_bf16(a0h, bl, acc[0][nt], 0, 0, 0);
            acc[1][nt] = __builtin_amdgcn_mfma_f32_16x16x32_bf16(a1h, bh, acc[1][nt], 0, 0, 0);
            acc[1][nt] = __builtin_amdgcn_mfma_f32_16x16x32_bf16(a1h, bl, acc[1][nt], 0, 0, 0);
        }
    }

    if (wv < 4) {
#pragma unroll
        for (int mt = 0; mt < 2; mt++)
#pragma unroll
            for (int nt = 0; nt < NT; nt++)
#pragma unroll
                for (int i = 0; i < 4; i++)
                    S[wv][mt * 16 + quad * 4 + i][nt * 16 + m] = acc[mt][nt][i];
    }
    __syncthreads();
    if (wv >= 4) {
#pragma unroll
        for (int mt = 0; mt < 2; mt++)
#pragma unroll
            for (int nt = 0; nt < NT; nt++)
#pragma unroll
                for (int i = 0; i < 4; i++)
                    S[wv - 4][mt * 16 + quad * 4 + i][nt * 16 + m] += acc[mt][nt][i];
    }
    __syncthreads();

    // phase 2: T4 rows -> M0 cols 0..31 + stash in S[0]
    for (int e = tid; e < 256; e += 512) {
        int e4 = e * 4;
        int n = e4 / DC, d = e4 % DC;
        float4 s0 = *(const float4*)&S[0][n][d];
        float4 s1 = *(const float4*)&S[1][n][d];
        float4 s2 = *(const float4*)&S[2][n][d];
        float4 s3 = *(const float4*)&S[3][n][d];
        float4 pv = *(const float4*)&prevF[((size_t)pair * NPTS + r0 + n) * 32 + d];
        float r = rdegS[n];
        float4 o = make_float4(0.5f * pv.x + r * (s0.x + s1.x + s2.x + s3.x),
                               0.5f * pv.y + r * (s0.y + s1.y + s2.y + s3.y),
                               0.5f * pv.z + r * (s0.z + s1.z + s2.z + s3.z),
                               0.5f * pv.w + r * (s0.w + s1.w + s2.w + s3.w));
        *(float4*)&M0[((size_t)pair * NPTS + r0 + n) * 96 + d] = o;
        *(float4*)&S[0][n][d] = o;
    }
    __syncthreads();

    // build-M0 tail: f0 = |A1-A2|, f1 = |A2-T4|; M0 cols 32..95; SB[feature][point] transposed
    if (tid < 256) {
        int dn = tid >> 3, dq = (tid & 7) * 4;
        size_t pn = (size_t)pair * NPTS + r0 + dn;
        float4 a1 = *(const float4*)&A1[pn * 32 + dq];
        float4 a2 = *(const float4*)&A2[pn * 32 + dq];
        float4 t4 = *(const float4*)&S[0][dn][dq];
        float4 f0 = make_float4(fabsf(a1.x - a2.x), fabsf(a1.y - a2.y), fabsf(a1.z - a2.z), fabsf(a1.w - a2.w));
        float4 f1 = make_float4(fabsf(a2.x - t4.x), fabsf(a2.y - t4.y), fabsf(a2.z - t4.z), fabsf(a2.w - t4.w));
        *(float4*)&M0[pn * 96 + 32 + dq] = f0;
        *(float4*)&M0[pn * 96 + 64 + dq] = f1;
        SB[dq][dn] = t4.x; SB[dq + 1][dn] = t4.y; SB[dq + 2][dn] = t4.z; SB[dq + 3][dn] = t4.w;
        SB[32 + dq][dn] = f0.x; SB[33 + dq][dn] = f0.y; SB[34 + dq][dn] = f0.z; SB[35 + dq][dn] = f0.w;
        SB[64 + dq][dn] = f1.x; SB[65 + dq][dn] = f1.y; SB[66 + dq][dn] = f1.z; SB[67 + dq][dn] = f1.w;
    }
    __syncthreads();

    // pool partials groups 1 (f0) and 2 (f1)
    if (tid < 64) {
        int gg = tid >> 5, d = tid & 31;
        float s = 0.f;
#pragma unroll
        for (int k = 0; k < 32; k++) s += SB[32 + gg * 32 + d][k];
        poolP[(((size_t)(1 + gg) * NPAIR + pair) * 32 + rt) * 32 + d] = s;
    }

    // phase 3: transposed bf16 hi/lo of all 96 M0 rows, fragment order (NF=6)
    for (int e = tid; e < 96 * 4; e += 512) {
        int row = e >> 2, nq = (e & 3) * 8;
        ushort8v hv, lv;
#pragma unroll
        for (int j = 0; j < 8; j++) {
            float v = SB[row][nq + j];
            u16 hb = bf16_rne(v);
            hv[j] = hb;
            lv[j] = bf16_rne(v - bf16_to_f32(hb));
        }
        int c0 = r0 + nq;
        size_t o = ((((size_t)pair * 6 + (row >> 4)) * 32 + (c0 >> 5)) << 9)
                 + (size_t)((((c0 >> 3) & 3) * 16 + (row & 15))) * 8;
        *(ushort8v*)(hiT + o) = hv;
        *(ushort8v*)(loT + o) = lv;
    }
}

// ============ fat apply N4: DC=64 apply -> Z8, + pool groups 3..6 ============
__global__ __launch_bounds__(512, 4) void apply_fused_pool(const u8* __restrict__ W8,
                                                           const u16* __restrict__ Yhi,
                                                           const u16* __restrict__ Ylo,
                                                           const float* __restrict__ deg,
                                                           const float* __restrict__ prevF,  // F96a, stride 64
                                                           float* __restrict__ Z8,           // stride 64
                                                           const float* __restrict__ M0,
                                                           const float* __restrict__ M2p,
                                                           const float* __restrict__ M4f,
                                                           float* __restrict__ poolP) {
    constexpr int DC = 64, NT = 4, SP = 68;
    __shared__ float S[4][32][SP];
    __shared__ float rdegS[32];
    __shared__ float PP[4][2][32];
    int bid = blockIdx.x;
    int pair = (bid & 7) * 2 + ((bid >> 3) & 1);
    int r0 = (bid >> 4) * 32;
    int rt = bid >> 4;
    int tid = threadIdx.x;
    int wv = tid >> 6, lane = tid & 63;
    int m = lane & 15, quad = lane >> 4;

    if (tid < 32) rdegS[tid] = 0.5f / deg[pair * NPTS + r0 + tid];

    int rt0 = rt * 2;
    const u8*  Wb  = W8  + ((((size_t)pair * 64 + rt0) * 32 + wv * 4) << 9) + (size_t)lane * 8;
    const u16* Ybh = Yhi + (((size_t)pair * NT * 32 + wv * 4) << 9) + (size_t)lane * 8;
    const u16* Ybl = Ylo + (((size_t)pair * NT * 32 + wv * 4) << 9) + (size_t)lane * 8;

    f32x4 acc[2][NT];
#pragma unroll
    for (int mt = 0; mt < 2; mt++)
#pragma unroll
        for (int nt = 0; nt < NT; nt++)
#pragma unroll
            for (int i = 0; i < 4; i++) acc[mt][nt][i] = 0.0f;

#pragma unroll 2
    for (int c = 0; c < 4; c++) {
        uint2 a0q = *(const uint2*)(Wb + ((size_t)c << 9));
        uint2 a1q = *(const uint2*)(Wb + ((size_t)(32 + c) << 9));
        short8 a0h = unpack_w8(a0q.x, a0q.y);
        short8 a1h = unpack_w8(a1q.x, a1q.y);
#pragma unroll
        for (int nt = 0; nt < NT; nt++) {
            short8 bh = *(const short8*)(Ybh + ((size_t)(nt * 32 + c) << 9));
            short8 bl = *(const short8*)(Ybl + ((size_t)(nt * 32 + c) << 9));
            acc[0][nt] = __builtin_amdgcn_mfma_f32_16x16x32_bf16(a0h, bh, acc[0][nt], 0, 0, 0);
            acc[0][nt] = __builtin_amdgcn_mfma_f32_16x16x32_bf16(a0h, bl, acc[0][nt], 0, 0, 0);
            acc[1][nt] = __builtin_amdgcn_mfma_f32_16x16x32_bf16(a1h, bh, acc[1][nt], 0, 0, 0);
            acc[1][nt] = __builtin_amdgcn_mfma_f32_16x16x32_bf16(a1h, bl, acc[1][nt], 0, 0, 0);
        }
    }

    if (wv < 4) {
#pragma unroll
        for (int mt = 0; mt < 2; mt++)
#pragma unroll
            for (int nt = 0; nt < NT; nt++)
#pragma unroll
                for (int i = 0; i < 4; i++)
                    S[wv][mt * 16 + quad * 4 + i][nt * 16 + m] = acc[mt][nt][i];
    }
    __syncthreads();
    if (wv >= 4) {
#pragma unroll
        for (int mt = 0; mt < 2; mt++)
#pragma unroll
            for (int nt = 0; nt < NT; nt++)
#pragma unroll
                for (int i = 0; i < 4; i++)
                    S[wv - 4][mt * 16 + quad * 4 + i][nt * 16 + m] += acc[mt][nt][i];
    }
    __syncthreads();

    for (int e = tid; e < 512; e += 512) {
        int e4 = e * 4;
        int n = e4 / DC, d = e4 % DC;
        float4 s0 = *(const float4*)&S[0][n][d];
        float4 s1 = *(const float4*)&S[1][n][d];
        float4 s2 = *(const float4*)&S[2][n][d];
        float4 s3 = *(const float4*)&S[3][n][d];
        float4 pv = *(const float4*)&prevF[((size_t)pair * NPTS + r0 + n) * 64 + d];
        float r = rdegS[n];
        float4 o = make_float4(0.5f * pv.x + r * (s0.x + s1.x + s2.x + s3.x),
                               0.5f * pv.y + r * (s0.y + s1.y + s2.y + s3.y),
                               0.5f * pv.z + r * (s0.z + s1.z + s2.z + s3.z),
                               0.5f * pv.w + r * (s0.w + s1.w + s2.w + s3.w));
        *(float4*)&Z8[((size_t)pair * NPTS + r0 + n) * 64 + d] = o;
        *(float4*)&S[0][n][d] = o;
    }
    __syncthreads();

    // pool partials groups 3..6 (Z8 read from S[0], rest from global rows r0..r0+32)
    if (tid < 256) {
        int gsel = tid >> 6, h = (tid >> 5) & 1, d = tid & 31;
        float s = 0.f;
#pragma unroll 4
        for (int k = 0; k < 16; k++) {
            int n = h * 16 + k;
            size_t pn = (size_t)pair * NPTS + r0 + n;
            float v;
            switch (gsel) {
                case 0: v = fabsf(M0[pn * 96 + d] - M4f[pn * 96 + d]); break;
                case 1: v = fabsf(M2p[pn * 32 + d] - M4f[pn * 96 + 32 + d]); break;
                case 2: v = fabsf(M4f[pn * 96 + 32 + d] - S[0][n][d]); break;
                default: v = fabsf(M4f[pn * 96 + 64 + d] - S[0][n][32 + d]); break;
            }
            s += v;
        }
        PP[gsel][h][d] = s;
    }
    __syncthreads();
    if (tid < 128) {
        int gsel = tid >> 5, d = tid & 31;
        poolP[(((size_t)(3 + gsel) * NPAIR + pair) * 32 + rt) * 32 + d] = PP[gsel][0][d] + PP[gsel][1][d];
    }
}

// ============ pool final: grid (NPAIR), block 256; reduce 32 rowtile partials ============
__global__ __launch_bounds__(256) void pool_final(const float* __restrict__ partial,
                                                  float* __restrict__ out) {
    int pair = blockIdx.x;
    int t = threadIdx.x;
    if (t < 224) {
        int g = t >> 5, d = t & 31;
        float s = 0.0f;
#pragma unroll 8
        for (int r = 0; r < 32; r++)
            s += partial[(((size_t)g * NPAIR + pair) * 32 + r) * 32 + d];
        out[(size_t)pair * 224 + t] = s * (1.0f / 1024.0f);
    }
}

extern "C" void kernel_launch(void* const* d_in, const int* in_sizes, int n_in,
                              void* d_out, int out_size, void* d_ws, size_t ws_size,
                              hipStream_t stream) {
    const float* pc     = (const float*)d_in[0];
    const float* alphas = (const float*)d_in[1];
    const float* sigp   = (const float*)d_in[2];
    float* out = (float*)d_out;
    float* ws = (float*)d_ws;

    // ---- workspace layout (unchanged sizes; W8/T* now fragment-ordered) ----
    float* X    = ws;                         // 524288
    float* sqX  = X + 524288;                 // 16384
    float* deg  = sqX + 16384;                // 16384
    u8* W8 = (u8*)(deg + 16384);              // 16777216 u8
    float* A1   = (float*)(W8 + 16777216);    // 524288
    float* A2   = A1 + 524288;                // 524288
    u16* T32a_h = (u16*)(A2 + 524288);        // 524288 u16 each
    u16* T32a_l = T32a_h + 524288;
    u16* T32b_h = T32a_l + 524288;
    u16* T32b_l = T32b_h + 524288;
    float* F96b = A1;                         // overlay (A1,A2,T32a_h/l dead by then)
    float* M0   = (float*)(T32b_l + 524288);  // 1572864
    float* M2p  = M0 + 1572864;               // 524288
    float* M4f  = M2p + 524288;               // 1572864
    float* Z8   = M4f + 1572864;              // 1048576
    float* F96a = Z8 + 1048576;               // 1572864  (also A3 overlay before M-chain)
    float* A3   = F96a;
    u16* T96a_h = (u16*)(F96a + 1572864);     // 1572864 u16 each
    u16* T96a_l = T96a_h + 1572864;
    u16* T96b_h = T96a_l + 1572864;
    u16* T96b_l = T96b_h + 1572864;
    u16* T64a_h = T96a_h;
    u16* T64a_l = T96a_l;
    u16* T64b_h = T96b_h;
    u16* T64b_l = T96b_l;
    float* poolP = (float*)(T96b_l + 1572864); // 7*16*32*32 = 114688 floats

    dim3 b256(256), b512(512);

    build_X<<<dim3(16, NPAIR), b256, 0, stream>>>(pc, alphas, X, sqX, deg, T32a_h, T32a_l, poolP);
    W_kernel<<<dim3(1024), b256, 0, stream>>>(X, sqX, sigp, deg, W8);

    // ---- A-chain (D=32) ----
    apply_fused<32><<<dim3(512), b512, 0, stream>>>(W8, T32a_h, T32a_l, deg,
                                             X, 32, 0, A1, 32, 0, nullptr, T32b_h, T32b_l, 0, 32);
    apply_fused<32><<<dim3(512), b512, 0, stream>>>(W8, T32b_h, T32b_l, deg,
                                             A1, 32, 0, A2, 32, 0, nullptr, T32a_h, T32a_l, 0, 32);
    apply_fused<32><<<dim3(512), b512, 0, stream>>>(W8, T32a_h, T32a_l, deg,
                                             A2, 32, 0, A3, 32, 0, nullptr, T32b_h, T32b_l, 0, 32);
    apply_fused_m0<<<dim3(512), b512, 0, stream>>>(W8, T32b_h, T32b_l, deg,
                                             A3, A1, A2, M0, T96a_h, T96a_l, poolP);

    // ---- M-chain (D=96) ----
    apply_fused<96><<<dim3(512), b512, 0, stream>>>(W8, T96a_h, T96a_l, deg,
                                             M0, 96, 0, F96a, 96, 0, nullptr, T96b_h, T96b_l, 0, 96);
    apply_fused<96><<<dim3(512), b512, 0, stream>>>(W8, T96b_h, T96b_l, deg,
                                             F96a, 96, 0, F96b, 96, 0, M2p, T96a_h, T96a_l, 0, 96);
    apply_fused<96><<<dim3(512), b512, 0, stream>>>(W8, T96a_h, T96a_l, deg,
                                             F96b, 96, 0, F96a, 96, 0, nullptr, T96b_h, T96b_l, 0, 96);
    apply_fused<96><<<dim3(512), b512, 0, stream>>>(W8, T96b_h, T96b_l, deg,
                                             F96a, 96, 0, M4f, 96, 0, nullptr, T64a_h, T64a_l, 32, 64);

    // ---- N-chain (D=64) ----
    apply_fused<64><<<dim3(512), b512, 0, stream>>>(W8, T64a_h, T64a_l, deg,
                                             M4f, 96, 32, F96a, 64, 0, nullptr, T64b_h, T64b_l, 0, 64);
    apply_fused<64><<<dim3(512), b512, 0, stream>>>(W8, T64b_h, T64b_l, deg,
                                             F96a, 64, 0, F96b, 64, 0, nullptr, T64a_h, T64a_l, 0, 64);
    apply_fused<64><<<dim3(512), b512, 0, stream>>>(W8, T64a_h, T64a_l, deg,
                                             F96b, 64, 0, F96a, 64, 0, nullptr, T64b_h, T64b_l, 0, 64);
    apply_fused_pool<<<dim3(512), b512, 0, stream>>>(W8, T64b_h, T64b_l, deg,
                                             F96a, Z8, M0, M2p, M4f, poolP);

    pool_final<<<dim3(NPAIR), b256, 0, stream>>>(poolP, out);
}

// Round 6
// 224.476 us; speedup vs baseline: 4.7971x; 1.0479x over previous
//
#include <hip/hip_runtime.h>
#include <math.h>

#define NPTS 1024
#define DIM 32
#define NPAIR 16   // B*NW

typedef __attribute__((ext_vector_type(8))) short short8;
typedef __attribute__((ext_vector_type(4))) float f32x4;
typedef __attribute__((ext_vector_type(8))) unsigned short ushort8v;
typedef unsigned short u16;
typedef unsigned char u8;

// ---------------- fragment-ordered layouts (MFMA-native) ----------------
// A-side (W8): fragment = 16 rows x 32 K u8. slot(lane) = quad*16 + m, lane holds 8 K-bytes.
//   addr = (((pair*64 + rowtile)*32 + ktile) << 9) + lane*8 + j          [bytes]
// B-side (T panels, u16): fragment = 16 features x 32 points (K).
//   addr = (((pair*NF + ftile)*32 + ktile) << 9) + lane*8 + j            [u16 units]
// Every wave k-loop load is then a contiguous 512B (A) / 1KB (B) block.

__device__ __forceinline__ u16 bf16_rne(float v) {
    unsigned u = __float_as_uint(v);
    return (u16)((u + 0x7fffu + ((u >> 16) & 1u)) >> 16);
}
__device__ __forceinline__ float bf16_to_f32(u16 b) {
    return __uint_as_float(((unsigned)b) << 16);
}

// u8 W (0..255) -> bf16 short8. Integers <=255 are exact in bf16.
__device__ __forceinline__ short8 unpack_w8(unsigned lo, unsigned hi) {
    short8 r;
#pragma unroll
    for (int j = 0; j < 4; j++) {
        float f0 = (float)((lo >> (8 * j)) & 0xffu);
        float f1 = (float)((hi >> (8 * j)) & 0xffu);
        r[j]     = (short)(__float_as_uint(f0) >> 16);
        r[j + 4] = (short)(__float_as_uint(f1) >> 16);
    }
    return r;
}

// ============ build_X: X + sqX + XT hi/lo (fragment order) + zero deg + pool group-0 ============
// grid (16 ntiles, NPAIR), block 256
__global__ __launch_bounds__(256) void build_X(const float* __restrict__ pc,
                                               const float* __restrict__ alphas,
                                               float* __restrict__ X,
                                               float* __restrict__ sqX,
                                               float* __restrict__ deg,
                                               u16* __restrict__ hiT,
                                               u16* __restrict__ loT,
                                               float* __restrict__ poolP) {
    __shared__ float S[DIM][68];
    int pair = blockIdx.y, n0 = blockIdx.x * 64, tid = threadIdx.x;
    int b = pair >> 2, w = pair & 3;
    for (int e = tid; e < 512; e += 256) {
        int e4 = e * 4;
        int dn = e4 >> 5, dq = e4 & 31;
        float4 p = *(const float4*)&pc[((size_t)b * NPTS + n0 + dn) * DIM + dq];
        float4 al = *(const float4*)&alphas[w * DIM + dq];
        float4 x = make_float4(p.x * al.x, p.y * al.y, p.z * al.z, p.w * al.w);
        *(float4*)&X[((size_t)pair * NPTS + n0 + dn) * DIM + dq] = x;
        S[dq][dn] = x.x; S[dq + 1][dn] = x.y; S[dq + 2][dn] = x.z; S[dq + 3][dn] = x.w;
    }
    __syncthreads();
    if (tid < 64) {
        float s = 0.f;
#pragma unroll
        for (int d = 0; d < DIM; d++) { float v = S[d][tid]; s += v * v; }
        sqX[pair * NPTS + n0 + tid] = s;
        deg[pair * NPTS + n0 + tid] = 0.0f;
    }
    if (tid < 64) {
        int h = tid >> 5, d = tid & 31;   // pool group 0
        float s = 0.f;
#pragma unroll
        for (int k = 0; k < 32; k++) s += S[d][h * 32 + k];
        poolP[(((size_t)0 * NPAIR + pair) * 32 + 2 * blockIdx.x + h) * 32 + d] = s;
    }
    for (int idx = tid; idx < DIM * 4; idx += 256) {
        int row = idx >> 2, nq = (idx & 3) * 16;
        ushort8v hv[2], lv[2];
#pragma unroll
        for (int i = 0; i < 16; i++) {
            float v = S[row][nq + i];
            u16 hb = bf16_rne(v);
            hv[i >> 3][i & 7] = hb;
            lv[i >> 3][i & 7] = bf16_rne(v - bf16_to_f32(hb));
        }
        // fragment-order write: points c0..c0+15 span quads q0, q0+1 of ktile kt
        int c0 = n0 + nq;
        int kt = c0 >> 5;
        int q0 = (c0 >> 3) & 3;        // 0 or 2
        int mm = row & 15;
        size_t base = ((((size_t)pair * 2 + (row >> 4)) * 32 + kt) << 9);   // NF=2
        *(ushort8v*)(hiT + base + (size_t)(q0 * 16 + mm) * 8)       = hv[0];
        *(ushort8v*)(hiT + base + (size_t)((q0 + 1) * 16 + mm) * 8) = hv[1];
        *(ushort8v*)(loT + base + (size_t)(q0 * 16 + mm) * 8)       = lv[0];
        *(ushort8v*)(loT + base + (size_t)((q0 + 1) * 16 + mm) * 8) = lv[1];
    }
}

// ============ W_kernel: W u8 fragment-order; deg = sum of quantized q ============
// grid 1024 blocks flat: xcd = b&7 -> pair = xcd*2 + (loc&1); block 256
__global__ __launch_bounds__(256, 4) void W_kernel(const float* __restrict__ X,
                                                   const float* __restrict__ sqX,
                                                   const float* __restrict__ sigp,
                                                   float* __restrict__ deg,
                                                   u8* __restrict__ W8) {
    int bid = blockIdx.x;
    int xcd = bid & 7, loc = bid >> 3;          // loc 0..127
    int pair = xcd * 2 + (loc & 1);
    int j0 = ((loc >> 1) & 3) * 256;
    int i0 = (loc >> 3) * 64;
    float rsig = -1.0f / (*sigp);
    const float* Xp = X + (size_t)pair * NPTS * DIM;

    __shared__ float XiT[DIM][68];
    __shared__ float XjT[DIM][68];
    __shared__ float sqjS[64];

    int tid = threadIdx.x;
    int cx = tid & 15, ry = tid >> 4;

    {
        int r = tid & 63, dgb = (tid >> 6) * 4;
#pragma unroll
        for (int p = 0; p < 2; p++) {
            int dg = dgb + p * 16;
            float4 v = *(const float4*)&Xp[(size_t)(i0 + r) * DIM + dg];
            XiT[dg][r] = v.x; XiT[dg + 1][r] = v.y; XiT[dg + 2][r] = v.z; XiT[dg + 3][r] = v.w;
        }
    }
    float sqi[4];
#pragma unroll
    for (int a = 0; a < 4; a++) sqi[a] = sqX[pair * NPTS + i0 + ry * 4 + a];

    float rs[4] = {0.f, 0.f, 0.f, 0.f};
#pragma unroll 1
    for (int jt = 0; jt < 256; jt += 64) {
        __syncthreads();
        {
            int r = tid & 63, dgb = (tid >> 6) * 4;
#pragma unroll
            for (int p = 0; p < 2; p++) {
                int dg = dgb + p * 16;
                float4 v = *(const float4*)&Xp[(size_t)(j0 + jt + r) * DIM + dg];
                XjT[dg][r] = v.x; XjT[dg + 1][r] = v.y; XjT[dg + 2][r] = v.z; XjT[dg + 3][r] = v.w;
            }
        }
        if (tid < 64) sqjS[tid] = sqX[pair * NPTS + j0 + jt + tid];
        __syncthreads();

        float dot[4][4] = {};
#pragma unroll
        for (int d = 0; d < DIM; d++) {
            float4 a = *(const float4*)&XiT[d][ry * 4];
            float4 b = *(const float4*)&XjT[d][cx * 4];
            dot[0][0] += a.x * b.x; dot[0][1] += a.x * b.y; dot[0][2] += a.x * b.z; dot[0][3] += a.x * b.w;
            dot[1][0] += a.y * b.x; dot[1][1] += a.y * b.y; dot[1][2] += a.y * b.z; dot[1][3] += a.y * b.w;
            dot[2][0] += a.z * b.x; dot[2][1] += a.z * b.y; dot[2][2] += a.z * b.z; dot[2][3] += a.z * b.w;
            dot[3][0] += a.w * b.x; dot[3][1] += a.w * b.y; dot[3][2] += a.w * b.z; dot[3][3] += a.w * b.w;
        }
#pragma unroll
        for (int a = 0; a < 4; a++) {
            int i = i0 + ry * 4 + a;
            int jb = j0 + jt + cx * 4;
            unsigned qw = 0;
#pragma unroll
            for (int bb = 0; bb < 4; bb++) {
                float Dm = sqi[a] + sqjS[cx * 4 + bb] - 2.0f * dot[a][bb];
                float K = __expf(Dm * rsig);
                float Wv = (K >= 0.5f) ? K : 0.0f;
                unsigned q = (unsigned)fmaf(Wv, 255.0f, 0.5f);   // 0 or 128..255
                rs[a] += (float)q;                                // deg tracks the QUANTIZED sum
                qw |= q << (8 * bb);
            }
            // fragment-order store: 4 K-bytes jb..jb+3 of row i
            int kt = jb >> 5;
            int quad = (jb >> 3) & 3;
            int jj = jb & 7;                     // 0 or 4
            size_t o = ((((size_t)pair * 64 + (i >> 4)) * 32 + kt) << 9)
                     + (size_t)(quad * 16 + (i & 15)) * 8 + jj;
            *(unsigned*)(W8 + o) = qw;
        }
    }
#pragma unroll
    for (int a = 0; a < 4; a++) {
        float s = rs[a];
        s += __shfl_xor(s, 1); s += __shfl_xor(s, 2);
        s += __shfl_xor(s, 4); s += __shfl_xor(s, 8);
        if (cx == 0) atomicAdd(&deg[pair * NPTS + i0 + ry * 4 + a], s);
    }
}

// ============ apply (DC=32, 32-row blocks, grid 512) — unchanged proven A-chain kernel ============
template <int DC>
__global__ __launch_bounds__(512, 4) void apply_fused(const u8* __restrict__ W8,
                                                      const u16* __restrict__ Yhi,
                                                      const u16* __restrict__ Ylo,
                                                      const float* __restrict__ deg,
                                                      const float* __restrict__ prevF,
                                                      int prevStride, int prevOff,
                                                      float* __restrict__ dstF,
                                                      int dstStride, int dstOff,
                                                      float* __restrict__ sliceF,
                                                      u16* __restrict__ hiT, u16* __restrict__ loT,
                                                      int tC0, int tCN) {
    constexpr int NT = DC / 16;
    constexpr int SP = DC + 4;
    __shared__ float S[4][32][SP];
    __shared__ float rdegS[32];
    int bid = blockIdx.x;
    int pair = (bid & 7) * 2 + ((bid >> 3) & 1);
    int r0 = (bid >> 4) * 32;
    int tid = threadIdx.x;
    int wv = tid >> 6, lane = tid & 63;
    int m = lane & 15, quad = lane >> 4;

    if (tid < 32) rdegS[tid] = 0.5f / deg[pair * NPTS + r0 + tid];

    int rt0 = (bid >> 4) * 2;
    const u8*  Wb  = W8  + ((((size_t)pair * 64 + rt0) * 32 + wv * 4) << 9) + (size_t)lane * 8;
    const u16* Ybh = Yhi + (((size_t)pair * NT * 32 + wv * 4) << 9) + (size_t)lane * 8;
    const u16* Ybl = Ylo + (((size_t)pair * NT * 32 + wv * 4) << 9) + (size_t)lane * 8;

    f32x4 acc[2][NT];
#pragma unroll
    for (int mt = 0; mt < 2; mt++)
#pragma unroll
        for (int nt = 0; nt < NT; nt++)
#pragma unroll
            for (int i = 0; i < 4; i++) acc[mt][nt][i] = 0.0f;

#pragma unroll 2
    for (int c = 0; c < 4; c++) {
        uint2 a0q = *(const uint2*)(Wb + ((size_t)c << 9));
        uint2 a1q = *(const uint2*)(Wb + ((size_t)(32 + c) << 9));
        short8 a0h = unpack_w8(a0q.x, a0q.y);
        short8 a1h = unpack_w8(a1q.x, a1q.y);
#pragma unroll
        for (int nt = 0; nt < NT; nt++) {
            short8 bh = *(const short8*)(Ybh + ((size_t)(nt * 32 + c) << 9));
            short8 bl = *(const short8*)(Ybl + ((size_t)(nt * 32 + c) << 9));
            acc[0][nt] = __builtin_amdgcn_mfma_f32_16x16x32_bf16(a0h, bh, acc[0][nt], 0, 0, 0);
            acc[0][nt] = __builtin_amdgcn_mfma_f32_16x16x32_bf16(a0h, bl, acc[0][nt], 0, 0, 0);
            acc[1][nt] = __builtin_amdgcn_mfma_f32_16x16x32_bf16(a1h, bh, acc[1][nt], 0, 0, 0);
            acc[1][nt] = __builtin_amdgcn_mfma_f32_16x16x32_bf16(a1h, bl, acc[1][nt], 0, 0, 0);
        }
    }

    if (wv < 4) {
#pragma unroll
        for (int mt = 0; mt < 2; mt++)
#pragma unroll
            for (int nt = 0; nt < NT; nt++)
#pragma unroll
                for (int i = 0; i < 4; i++)
                    S[wv][mt * 16 + quad * 4 + i][nt * 16 + m] = acc[mt][nt][i];
    }
    __syncthreads();
    if (wv >= 4) {
#pragma unroll
        for (int mt = 0; mt < 2; mt++)
#pragma unroll
            for (int nt = 0; nt < NT; nt++)
#pragma unroll
                for (int i = 0; i < 4; i++)
                    S[wv - 4][mt * 16 + quad * 4 + i][nt * 16 + m] += acc[mt][nt][i];
    }
    __syncthreads();

    constexpr int E2 = 32 * DC / 4;
    for (int e = tid; e < E2; e += 512) {
        int e4 = e * 4;
        int n = e4 / DC, d = e4 % DC;
        float4 s0 = *(const float4*)&S[0][n][d];
        float4 s1 = *(const float4*)&S[1][n][d];
        float4 s2 = *(const float4*)&S[2][n][d];
        float4 s3 = *(const float4*)&S[3][n][d];
        float4 pv = *(const float4*)&prevF[((size_t)pair * NPTS + r0 + n) * prevStride + prevOff + d];
        float r = rdegS[n];
        float4 o = make_float4(0.5f * pv.x + r * (s0.x + s1.x + s2.x + s3.x),
                               0.5f * pv.y + r * (s0.y + s1.y + s2.y + s3.y),
                               0.5f * pv.z + r * (s0.z + s1.z + s2.z + s3.z),
                               0.5f * pv.w + r * (s0.w + s1.w + s2.w + s3.w));
        *(float4*)&dstF[((size_t)pair * NPTS + r0 + n) * dstStride + dstOff + d] = o;
        if (sliceF && d >= 32 && d < 64)
            *(float4*)&sliceF[((size_t)pair * NPTS + r0 + n) * 32 + (d - 32)] = o;
        *(float4*)&S[0][n][d] = o;
    }
    __syncthreads();

    if (hiT) {
        int NFo = tCN >> 4;
        for (int e = tid; e < tCN * 4; e += 512) {
            int row = e >> 2, nq = (e & 3) * 8;
            ushort8v hv, lv;
#pragma unroll
            for (int j = 0; j < 8; j++) {
                float v = S[0][nq + j][tC0 + row];
                u16 hb = bf16_rne(v);
                hv[j] = hb;
                lv[j] = bf16_rne(v - bf16_to_f32(hb));
            }
            int c0 = r0 + nq;
            size_t o = ((((size_t)pair * NFo + (row >> 4)) * 32 + (c0 >> 5)) << 9)
                     + (size_t)((((c0 >> 3) & 3) * 16 + (row & 15))) * 8;
            *(ushort8v*)(hiT + o) = hv;
            *(ushort8v*)(loT + o) = lv;
        }
    }
}

// ============ apply2: 64-row x 32-col chunk blocks (AI=64, halved B traffic) ============
// grid 256*NCH flat: pair = (b&7)*2 + ((b>>3)&1), rseg = (b>>4)&15, chunk = b>>8; block 512
template <int DC>
__global__ __launch_bounds__(512, 4) void apply_fused2(const u8* __restrict__ W8,
                                                       const u16* __restrict__ Yhi,
                                                       const u16* __restrict__ Ylo,
                                                       const float* __restrict__ deg,
                                                       const float* __restrict__ prevF,
                                                       int prevStride, int prevOff,
                                                       float* __restrict__ dstF,
                                                       int dstStride, int dstOff,
                                                       float* __restrict__ sliceF,  // cols 32..63 (chunk 1)
                                                       u16* __restrict__ hiT, u16* __restrict__ loT,
                                                       int tC0, int tCN) {
    constexpr int NF = DC / 16;
    constexpr int SP = 36;
    __shared__ float S[4][64][SP];
    __shared__ float rdegS[64];
    int bid = blockIdx.x;
    int pair = (bid & 7) * 2 + ((bid >> 3) & 1);
    int rseg = (bid >> 4) & 15;
    int ch = bid >> 8;
    int r0 = rseg * 64;
    int tid = threadIdx.x;
    int wv = tid >> 6, lane = tid & 63;
    int m = lane & 15, quad = lane >> 4;

    if (tid < 64) rdegS[tid] = 0.5f / deg[pair * NPTS + r0 + tid];

    const u8*  Wb  = W8  + ((((size_t)pair * 64 + rseg * 4) * 32 + wv * 4) << 9) + (size_t)lane * 8;
    const u16* Ybh = Yhi + ((((size_t)pair * NF + ch * 2) * 32 + wv * 4) << 9) + (size_t)lane * 8;
    const u16* Ybl = Ylo + ((((size_t)pair * NF + ch * 2) * 32 + wv * 4) << 9) + (size_t)lane * 8;

    f32x4 acc[4][2];
#pragma unroll
    for (int mt = 0; mt < 4; mt++)
#pragma unroll
        for (int nt = 0; nt < 2; nt++)
#pragma unroll
            for (int i = 0; i < 4; i++) acc[mt][nt][i] = 0.0f;

#pragma unroll 2
    for (int c = 0; c < 4; c++) {
        uint2 aq[4];
#pragma unroll
        for (int mt = 0; mt < 4; mt++)
            aq[mt] = *(const uint2*)(Wb + ((size_t)(mt * 32 + c) << 9));
        short8 a[4];
#pragma unroll
        for (int mt = 0; mt < 4; mt++) a[mt] = unpack_w8(aq[mt].x, aq[mt].y);
#pragma unroll
        for (int nt = 0; nt < 2; nt++) {
            short8 bh = *(const short8*)(Ybh + ((size_t)(nt * 32 + c) << 9));
            short8 bl = *(const short8*)(Ybl + ((size_t)(nt * 32 + c) << 9));
#pragma unroll
            for (int mt = 0; mt < 4; mt++) {
                acc[mt][nt] = __builtin_amdgcn_mfma_f32_16x16x32_bf16(a[mt], bh, acc[mt][nt], 0, 0, 0);
                acc[mt][nt] = __builtin_amdgcn_mfma_f32_16x16x32_bf16(a[mt], bl, acc[mt][nt], 0, 0, 0);
            }
        }
    }

    // phase 1a: waves 0-3 deposit partial tiles (64 rows x 32 cols)
    if (wv < 4) {
#pragma unroll
        for (int mt = 0; mt < 4; mt++)
#pragma unroll
            for (int nt = 0; nt < 2; nt++)
#pragma unroll
                for (int i = 0; i < 4; i++)
                    S[wv][mt * 16 + quad * 4 + i][nt * 16 + m] = acc[mt][nt][i];
    }
    __syncthreads();
    // phase 1b: waves 4-7 add into planes 0-3
    if (wv >= 4) {
#pragma unroll
        for (int mt = 0; mt < 4; mt++)
#pragma unroll
            for (int nt = 0; nt < 2; nt++)
#pragma unroll
                for (int i = 0; i < 4; i++)
                    S[wv - 4][mt * 16 + quad * 4 + i][nt * 16 + m] += acc[mt][nt][i];
    }
    __syncthreads();

    // phase 2: one float4 per thread (64 rows x 32 cols / 4)
    {
        int n = tid >> 3, d = (tid & 7) * 4;
        int col = ch * 32 + d;
        float4 s0 = *(const float4*)&S[0][n][d];
        float4 s1 = *(const float4*)&S[1][n][d];
        float4 s2 = *(const float4*)&S[2][n][d];
        float4 s3 = *(const float4*)&S[3][n][d];
        float4 pv = *(const float4*)&prevF[((size_t)pair * NPTS + r0 + n) * prevStride + prevOff + col];
        float r = rdegS[n];
        float4 o = make_float4(0.5f * pv.x + r * (s0.x + s1.x + s2.x + s3.x),
                               0.5f * pv.y + r * (s0.y + s1.y + s2.y + s3.y),
                               0.5f * pv.z + r * (s0.z + s1.z + s2.z + s3.z),
                               0.5f * pv.w + r * (s0.w + s1.w + s2.w + s3.w));
        *(float4*)&dstF[((size_t)pair * NPTS + r0 + n) * dstStride + dstOff + col] = o;
        if (sliceF && ch == 1)
            *(float4*)&sliceF[((size_t)pair * NPTS + r0 + n) * 32 + d] = o;
        *(float4*)&S[0][n][d] = o;
    }
    __syncthreads();

    // phase 3: transposed bf16 hi/lo for this chunk's 32 feature rows (if in T range)
    int gr0 = 32 * ch - tC0;
    if (hiT && gr0 >= 0 && gr0 < tCN) {
        int NFo = tCN >> 4;
        if (tid < 256) {
            int lr = tid >> 3, nq = (tid & 7) * 8;
            ushort8v hv, lv;
#pragma unroll
            for (int j = 0; j < 8; j++) {
                float v = S[0][nq + j][lr];
                u16 hb = bf16_rne(v);
                hv[j] = hb;
                lv[j] = bf16_rne(v - bf16_to_f32(hb));
            }
            int gr = gr0 + lr;
            int c0 = r0 + nq;
            size_t o = ((((size_t)pair * NFo + (gr >> 4)) * 32 + (c0 >> 5)) << 9)
                     + (size_t)((((c0 >> 3) & 3) * 16 + (gr & 15))) * 8;
            *(ushort8v*)(hiT + o) = hv;
            *(ushort8v*)(loT + o) = lv;
        }
    }
}

// ============ fat apply A4 (DC=32, 32-row blocks, grid 512) — unchanged proven kernel ============
__global__ __launch_bounds__(512, 4) void apply_fused_m0(const u8* __restrict__ W8,
                                                         const u16* __restrict__ Yhi,
                                                         const u16* __restrict__ Ylo,
                                                         const float* __restrict__ deg,
                                                         const float* __restrict__ prevF,   // A3, stride 32
                                                         const float* __restrict__ A1,
                                                         const float* __restrict__ A2,
                                                         float* __restrict__ M0,            // stride 96
                                                         u16* __restrict__ hiT, u16* __restrict__ loT,  // T96a
                                                         float* __restrict__ poolP) {
    constexpr int DC = 32, NT = 2, SP = 36;
    __shared__ float S[4][32][SP];
    __shared__ float rdegS[32];
    __shared__ float SB[96][33];
    int bid = blockIdx.x;
    int pair = (bid & 7) * 2 + ((bid >> 3) & 1);
    int r0 = (bid >> 4) * 32;
    int rt = bid >> 4;
    int tid = threadIdx.x;
    int wv = tid >> 6, lane = tid & 63;
    int m = lane & 15, quad = lane >> 4;

    if (tid < 32) rdegS[tid] = 0.5f / deg[pair * NPTS + r0 + tid];

    int rt0 = rt * 2;
    const u8*  Wb  = W8  + ((((size_t)pair * 64 + rt0) * 32 + wv * 4) << 9) + (size_t)lane * 8;
    const u16* Ybh = Yhi + (((size_t)pair * NT * 32 + wv * 4) << 9) + (size_t)lane * 8;
    const u16* Ybl = Ylo + (((size_t)pair * NT * 32 + wv * 4) << 9) + (size_t)lane * 8;

    f32x4 acc[2][NT];
#pragma unroll
    for (int mt = 0; mt < 2; mt++)
#pragma unroll
        for (int nt = 0; nt < NT; nt++)
#pragma unroll
            for (int i = 0; i < 4; i++) acc[mt][nt][i] = 0.0f;

#pragma unroll 2
    for (int c = 0; c < 4; c++) {
        uint2 a0q = *(const uint2*)(Wb + ((size_t)c << 9));
        uint2 a1q = *(const uint2*)(Wb + ((size_t)(32 + c) << 9));
        short8 a0h = unpack_w8(a0q.x, a0q.y);
        short8 a1h = unpack_w8(a1q.x, a1q.y);
#pragma unroll
        for (int nt = 0; nt < NT; nt++) {
            short8 bh = *(const short8*)(Ybh + ((size_t)(nt * 32 + c) << 9));
            short8 bl = *(const short8*)(Ybl + ((size_t)(nt * 32 + c) << 9));
            acc[0][nt] = __builtin_amdgcn_mfma_f32_16x16x32_bf16(a0h, bh, acc[0][nt], 0, 0, 0);
            acc[0][nt] = __builtin_amdgcn_mfma_f32_16x16x32_bf16(a0h, bl, acc[0][nt], 0, 0, 0);
            acc[1][nt] = __builtin_amdgcn_mfma_f32_16x16x32_bf16(a1h, bh, acc[1][nt], 0, 0, 0);
            acc[1][nt] = __builtin_amdgcn_mfma_f32_16x16x32_bf16(a1h, bl, acc[1][nt], 0, 0, 0);
        }
    }

    if (wv < 4) {
#pragma unroll
        for (int mt = 0; mt < 2; mt++)
#pragma unroll
            for (int nt = 0; nt < NT; nt++)
#pragma unroll
                for (int i = 0; i < 4; i++)
                    S[wv][mt * 16 + quad * 4 + i][nt * 16 + m] = acc[mt][nt][i];
    }
    __syncthreads();
    if (wv >= 4) {
#pragma unroll
        for (int mt = 0; mt < 2; mt++)
#pragma unroll
            for (int nt = 0; nt < NT; nt++)
#pragma unroll
                for (int i = 0; i < 4; i++)
                    S[wv - 4][mt * 16 + quad * 4 + i][nt * 16 + m] += acc[mt][nt][i];
    }
    __syncthreads();

    for (int e = tid; e < 256; e += 512) {
        int e4 = e * 4;
        int n = e4 / DC, d = e4 % DC;
        float4 s0 = *(const float4*)&S[0][n][d];
        float4 s1 = *(const float4*)&S[1][n][d];
        float4 s2 = *(const float4*)&S[2][n][d];
        float4 s3 = *(const float4*)&S[3][n][d];
        float4 pv = *(const float4*)&prevF[((size_t)pair * NPTS + r0 + n) * 32 + d];
        float r = rdegS[n];
        float4 o = make_float4(0.5f * pv.x + r * (s0.x + s1.x + s2.x + s3.x),
                               0.5f * pv.y + r * (s0.y + s1.y + s2.y + s3.y),
                               0.5f * pv.z + r * (s0.z + s1.z + s2.z + s3.z),
                               0.5f * pv.w + r * (s0.w + s1.w + s2.w + s3.w));
        *(float4*)&M0[((size_t)pair * NPTS + r0 + n) * 96 + d] = o;
        *(float4*)&S[0][n][d] = o;
    }
    __syncthreads();

    if (tid < 256) {
        int dn = tid >> 3, dq = (tid & 7) * 4;
        size_t pn = (size_t)pair * NPTS + r0 + dn;
        float4 a1 = *(const float4*)&A1[pn * 32 + dq];
        float4 a2 = *(const float4*)&A2[pn * 32 + dq];
        float4 t4 = *(const float4*)&S[0][dn][dq];
        float4 f0 = make_float4(fabsf(a1.x - a2.x), fabsf(a1.y - a2.y), fabsf(a1.z - a2.z), fabsf(a1.w - a2.w));
        float4 f1 = make_float4(fabsf(a2.x - t4.x), fabsf(a2.y - t4.y), fabsf(a2.z - t4.z), fabsf(a2.w - t4.w));
        *(float4*)&M0[pn * 96 + 32 + dq] = f0;
        *(float4*)&M0[pn * 96 + 64 + dq] = f1;
        SB[dq][dn] = t4.x; SB[dq + 1][dn] = t4.y; SB[dq + 2][dn] = t4.z; SB[dq + 3][dn] = t4.w;
        SB[32 + dq][dn] = f0.x; SB[33 + dq][dn] = f0.y; SB[34 + dq][dn] = f0.z; SB[35 + dq][dn] = f0.w;
        SB[64 + dq][dn] = f1.x; SB[65 + dq][dn] = f1.y; SB[66 + dq][dn] = f1.z; SB[67 + dq][dn] = f1.w;
    }
    __syncthreads();

    if (tid < 64) {
        int gg = tid >> 5, d = tid & 31;
        float s = 0.f;
#pragma unroll
        for (int k = 0; k < 32; k++) s += SB[32 + gg * 32 + d][k];
        poolP[(((size_t)(1 + gg) * NPAIR + pair) * 32 + rt) * 32 + d] = s;
    }

    for (int e = tid; e < 96 * 4; e += 512) {
        int row = e >> 2, nq = (e & 3) * 8;
        ushort8v hv, lv;
#pragma unroll
        for (int j = 0; j < 8; j++) {
            float v = SB[row][nq + j];
            u16 hb = bf16_rne(v);
            hv[j] = hb;
            lv[j] = bf16_rne(v - bf16_to_f32(hb));
        }
        int c0 = r0 + nq;
        size_t o = ((((size_t)pair * 6 + (row >> 4)) * 32 + (c0 >> 5)) << 9)
                 + (size_t)((((c0 >> 3) & 3) * 16 + (row & 15))) * 8;
        *(ushort8v*)(hiT + o) = hv;
        *(ushort8v*)(loT + o) = lv;
    }
}

// ============ fat apply N4: apply2<64> core -> Z8, + pool groups 3..6 ============
// grid 512 (= 256 x 2 chunks): ch0 blocks do groups 3,4,5; ch1 blocks do group 6
__global__ __launch_bounds__(512, 4) void apply_fused_pool2(const u8* __restrict__ W8,
                                                            const u16* __restrict__ Yhi,
                                                            const u16* __restrict__ Ylo,
                                                            const float* __restrict__ deg,
                                                            const float* __restrict__ prevF,  // F96a, stride 64
                                                            float* __restrict__ Z8,           // stride 64
                                                            const float* __restrict__ M0,
                                                            const float* __restrict__ M2p,
                                                            const float* __restrict__ M4f,
                                                            float* __restrict__ poolP) {
    constexpr int NF = 4, SP = 36;
    __shared__ float S[4][64][SP];
    __shared__ float rdegS[64];
    int bid = blockIdx.x;
    int pair = (bid & 7) * 2 + ((bid >> 3) & 1);
    int rseg = (bid >> 4) & 15;
    int ch = bid >> 8;
    int r0 = rseg * 64;
    int tid = threadIdx.x;
    int wv = tid >> 6, lane = tid & 63;
    int m = lane & 15, quad = lane >> 4;

    if (tid < 64) rdegS[tid] = 0.5f / deg[pair * NPTS + r0 + tid];

    const u8*  Wb  = W8  + ((((size_t)pair * 64 + rseg * 4) * 32 + wv * 4) << 9) + (size_t)lane * 8;
    const u16* Ybh = Yhi + ((((size_t)pair * NF + ch * 2) * 32 + wv * 4) << 9) + (size_t)lane * 8;
    const u16* Ybl = Ylo + ((((size_t)pair * NF + ch * 2) * 32 + wv * 4) << 9) + (size_t)lane * 8;

    f32x4 acc[4][2];
#pragma unroll
    for (int mt = 0; mt < 4; mt++)
#pragma unroll
        for (int nt = 0; nt < 2; nt++)
#pragma unroll
            for (int i = 0; i < 4; i++) acc[mt][nt][i] = 0.0f;

#pragma unroll 2
    for (int c = 0; c < 4; c++) {
        uint2 aq[4];
#pragma unroll
        for (int mt = 0; mt < 4; mt++)
            aq[mt] = *(const uint2*)(Wb + ((size_t)(mt * 32 + c) << 9));
        short8 a[4];
#pragma unroll
        for (int mt = 0; mt < 4; mt++) a[mt] = unpack_w8(aq[mt].x, aq[mt].y);
#pragma unroll
        for (int nt = 0; nt < 2; nt++) {
            short8 bh = *(const short8*)(Ybh + ((size_t)(nt * 32 + c) << 9));
            short8 bl = *(const short8*)(Ybl + ((size_t)(nt * 32 + c) << 9));
#pragma unroll
            for (int mt = 0; mt < 4; mt++) {
                acc[mt][nt] = __builtin_amdgcn_mfma_f32_16x16x32_bf16(a[mt], bh, acc[mt][nt], 0, 0, 0);
                acc[mt][nt] = __builtin_amdgcn_mfma_f32_16x16x32_bf16(a[mt], bl, acc[mt][nt], 0, 0, 0);
            }
        }
    }

    if (wv < 4) {
#pragma unroll
        for (int mt = 0; mt < 4; mt++)
#pragma unroll
            for (int nt = 0; nt < 2; nt++)
#pragma unroll
                for (int i = 0; i < 4; i++)
                    S[wv][mt * 16 + quad * 4 + i][nt * 16 + m] = acc[mt][nt][i];
    }
    __syncthreads();
    if (wv >= 4) {
#pragma unroll
        for (int mt = 0; mt < 4; mt++)
#pragma unroll
            for (int nt = 0; nt < 2; nt++)
#pragma unroll
                for (int i = 0; i < 4; i++)
                    S[wv - 4][mt * 16 + quad * 4 + i][nt * 16 + m] += acc[mt][nt][i];
    }
    __syncthreads();

    {
        int n = tid >> 3, d = (tid & 7) * 4;
        int col = ch * 32 + d;
        float4 s0 = *(const float4*)&S[0][n][d];
        float4 s1 = *(const float4*)&S[1][n][d];
        float4 s2 = *(const float4*)&S[2][n][d];
        float4 s3 = *(const float4*)&S[3][n][d];
        float4 pv = *(const float4*)&prevF[((size_t)pair * NPTS + r0 + n) * 64 + col];
        float r = rdegS[n];
        float4 o = make_float4(0.5f * pv.x + r * (s0.x + s1.x + s2.x + s3.x),
                               0.5f * pv.y + r * (s0.y + s1.y + s2.y + s3.y),
                               0.5f * pv.z + r * (s0.z + s1.z + s2.z + s3.z),
                               0.5f * pv.w + r * (s0.w + s1.w + s2.w + s3.w));
        *(float4*)&Z8[((size_t)pair * NPTS + r0 + n) * 64 + col] = o;
        *(float4*)&S[0][n][d] = o;
    }
    __syncthreads();

    // pool partials: per 32-point half h -> slot 2*rseg + h (keeps poolP layout at 32 slots)
    if (ch == 0) {
        if (tid < 192) {
            int gsel = tid >> 6, h = (tid >> 5) & 1, d = tid & 31;
            float s = 0.f;
#pragma unroll 4
            for (int k = 0; k < 32; k++) {
                int n = h * 32 + k;
                size_t pn = (size_t)pair * NPTS + r0 + n;
                float v;
                switch (gsel) {
                    case 0: v = fabsf(M0[pn * 96 + d] - M4f[pn * 96 + d]); break;
                    case 1: v = fabsf(M2p[pn * 32 + d] - M4f[pn * 96 + 32 + d]); break;
                    default: v = fabsf(M4f[pn * 96 + 32 + d] - S[0][n][d]); break;
                }
                s += v;
            }
            poolP[(((size_t)(3 + gsel) * NPAIR + pair) * 32 + 2 * rseg + h) * 32 + d] = s;
        }
    } else {
        if (tid < 64) {
            int h = tid >> 5, d = tid & 31;
            float s = 0.f;
#pragma unroll 4
            for (int k = 0; k < 32; k++) {
                int n = h * 32 + k;
                size_t pn = (size_t)pair * NPTS + r0 + n;
                s += fabsf(M4f[pn * 96 + 64 + d] - S[0][n][d]);   // S[0] holds Z8 cols 32..63
            }
            poolP[(((size_t)6 * NPAIR + pair) * 32 + 2 * rseg + h) * 32 + d] = s;
        }
    }
}

// ============ pool final: grid (NPAIR), block 256; reduce 32 slot partials ============
__global__ __launch_bounds__(256) void pool_final(const float* __restrict__ partial,
                                                  float* __restrict__ out) {
    int pair = blockIdx.x;
    int t = threadIdx.x;
    if (t < 224) {
        int g = t >> 5, d = t & 31;
        float s = 0.0f;
#pragma unroll 8
        for (int r = 0; r < 32; r++)
            s += partial[(((size_t)g * NPAIR + pair) * 32 + r) * 32 + d];
        out[(size_t)pair * 224 + t] = s * (1.0f / 1024.0f);
    }
}

extern "C" void kernel_launch(void* const* d_in, const int* in_sizes, int n_in,
                              void* d_out, int out_size, void* d_ws, size_t ws_size,
                              hipStream_t stream) {
    const float* pc     = (const float*)d_in[0];
    const float* alphas = (const float*)d_in[1];
    const float* sigp   = (const float*)d_in[2];
    float* out = (float*)d_out;
    float* ws = (float*)d_ws;

    // ---- workspace layout (unchanged; W8/T* fragment-ordered) ----
    float* X    = ws;                         // 524288
    float* sqX  = X + 524288;                 // 16384
    float* deg  = sqX + 16384;                // 16384
    u8* W8 = (u8*)(deg + 16384);              // 16777216 u8
    float* A1   = (float*)(W8 + 16777216);    // 524288
    float* A2   = A1 + 524288;                // 524288
    u16* T32a_h = (u16*)(A2 + 524288);        // 524288 u16 each
    u16* T32a_l = T32a_h + 524288;
    u16* T32b_h = T32a_l + 524288;
    u16* T32b_l = T32b_h + 524288;
    float* F96b = A1;                         // overlay (A1,A2,T32a_h/l dead by then)
    float* M0   = (float*)(T32b_l + 524288);  // 1572864
    float* M2p  = M0 + 1572864;               // 524288
    float* M4f  = M2p + 524288;               // 1572864
    float* Z8   = M4f + 1572864;              // 1048576
    float* F96a = Z8 + 1048576;               // 1572864  (also A3 overlay before M-chain)
    float* A3   = F96a;
    u16* T96a_h = (u16*)(F96a + 1572864);     // 1572864 u16 each
    u16* T96a_l = T96a_h + 1572864;
    u16* T96b_h = T96a_l + 1572864;
    u16* T96b_l = T96b_h + 1572864;
    u16* T64a_h = T96a_h;
    u16* T64a_l = T96a_l;
    u16* T64b_h = T96b_h;
    u16* T64b_l = T96b_l;
    float* poolP = (float*)(T96b_l + 1572864); // 7*16*32*32 = 114688 floats

    dim3 b256(256), b512(512);

    build_X<<<dim3(16, NPAIR), b256, 0, stream>>>(pc, alphas, X, sqX, deg, T32a_h, T32a_l, poolP);
    W_kernel<<<dim3(1024), b256, 0, stream>>>(X, sqX, sigp, deg, W8);

    // ---- A-chain (D=32): unchanged 32-row kernels ----
    apply_fused<32><<<dim3(512), b512, 0, stream>>>(W8, T32a_h, T32a_l, deg,
                                             X, 32, 0, A1, 32, 0, nullptr, T32b_h, T32b_l, 0, 32);
    apply_fused<32><<<dim3(512), b512, 0, stream>>>(W8, T32b_h, T32b_l, deg,
                                             A1, 32, 0, A2, 32, 0, nullptr, T32a_h, T32a_l, 0, 32);
    apply_fused<32><<<dim3(512), b512, 0, stream>>>(W8, T32a_h, T32a_l, deg,
                                             A2, 32, 0, A3, 32, 0, nullptr, T32b_h, T32b_l, 0, 32);
    apply_fused_m0<<<dim3(512), b512, 0, stream>>>(W8, T32b_h, T32b_l, deg,
                                             A3, A1, A2, M0, T96a_h, T96a_l, poolP);

    // ---- M-chain (D=96): 64-row chunk-split, grid 768 ----
    apply_fused2<96><<<dim3(768), b512, 0, stream>>>(W8, T96a_h, T96a_l, deg,
                                             M0, 96, 0, F96a, 96, 0, nullptr, T96b_h, T96b_l, 0, 96);
    apply_fused2<96><<<dim3(768), b512, 0, stream>>>(W8, T96b_h, T96b_l, deg,
                                             F96a, 96, 0, F96b, 96, 0, M2p, T96a_h, T96a_l, 0, 96);
    apply_fused2<96><<<dim3(768), b512, 0, stream>>>(W8, T96a_h, T96a_l, deg,
                                             F96b, 96, 0, F96a, 96, 0, nullptr, T96b_h, T96b_l, 0, 96);
    apply_fused2<96><<<dim3(768), b512, 0, stream>>>(W8, T96b_h, T96b_l, deg,
                                             F96a, 96, 0, M4f, 96, 0, nullptr, T64a_h, T64a_l, 32, 64);

    // ---- N-chain (D=64): 64-row chunk-split, grid 512 ----
    apply_fused2<64><<<dim3(512), b512, 0, stream>>>(W8, T64a_h, T64a_l, deg,
                                             M4f, 96, 32, F96a, 64, 0, nullptr, T64b_h, T64b_l, 0, 64);
    apply_fused2<64><<<dim3(512), b512, 0, stream>>>(W8, T64b_h, T64b_l, deg,
                                             F96a, 64, 0, F96b, 64, 0, nullptr, T64a_h, T64a_l, 0, 64);
    apply_fused2<64><<<dim3(512), b512, 0, stream>>>(W8, T64a_h, T64a_l, deg,
                                             F96b, 64, 0, F96a, 64, 0, nullptr, T64b_h, T64b_l, 0, 64);
    apply_fused_pool2<<<dim3(512), b512, 0, stream>>>(W8, T64b_h, T64b_l, deg,
                                             F96a, Z8, M0, M2p, M4f, poolP);

    pool_final<<<dim3(NPAIR), b256, 0, stream>>>(poolP, out);
}

// Round 7
// 211.922 us; speedup vs baseline: 5.0812x; 1.0592x over previous
//
#include <hip/hip_runtime.h>
#include <math.h>

#define NPTS 1024
#define DIM 32
#define NPAIR 16   // B*NW

typedef __attribute__((ext_vector_type(8))) short short8;
typedef __attribute__((ext_vector_type(4))) float f32x4;
typedef __attribute__((ext_vector_type(8))) unsigned short ushort8v;
typedef __attribute__((ext_vector_type(4))) unsigned short ushort4v;
typedef unsigned short u16;
typedef unsigned char u8;

// ---------------- fragment-ordered layouts (MFMA-native) ----------------
// A-side (W8): fragment = 16 rows x 32 K u8. slot(lane) = quad*16 + m, lane holds 8 K-bytes.
//   addr = (((pair*64 + rowtile)*32 + ktile) << 9) + lane*8 + j          [bytes]
// B-side (T panels, u16): fragment = 16 features x 32 points (K).
//   addr = (((pair*NF + ftile)*32 + ktile) << 9) + lane*8 + j            [u16 units]
// Row-major bf16 X (Xb_h/Xb_l) is NATIVELY fragment-ordered for 16x16x32
// (both operands want 16 rows x 32 K = 1KB contiguous per fragment).

__device__ __forceinline__ u16 bf16_rne(float v) {
    unsigned u = __float_as_uint(v);
    return (u16)((u + 0x7fffu + ((u >> 16) & 1u)) >> 16);
}
__device__ __forceinline__ float bf16_to_f32(u16 b) {
    return __uint_as_float(((unsigned)b) << 16);
}

// u8 W (0..255) -> bf16 short8. Integers <=255 are exact in bf16.
__device__ __forceinline__ short8 unpack_w8(unsigned lo, unsigned hi) {
    short8 r;
#pragma unroll
    for (int j = 0; j < 4; j++) {
        float f0 = (float)((lo >> (8 * j)) & 0xffu);
        float f1 = (float)((hi >> (8 * j)) & 0xffu);
        r[j]     = (short)(__float_as_uint(f0) >> 16);
        r[j + 4] = (short)(__float_as_uint(f1) >> 16);
    }
    return r;
}

// ============ build_X: X + Xb hi/lo (row bf16) + sqX + XT hi/lo + zero deg + pool g0 ============
// grid (16 ntiles, NPAIR), block 256
__global__ __launch_bounds__(256) void build_X(const float* __restrict__ pc,
                                               const float* __restrict__ alphas,
                                               float* __restrict__ X,
                                               u16* __restrict__ Xbh,
                                               u16* __restrict__ Xbl,
                                               float* __restrict__ sqX,
                                               float* __restrict__ deg,
                                               u16* __restrict__ hiT,
                                               u16* __restrict__ loT,
                                               float* __restrict__ poolP) {
    __shared__ float S[DIM][68];
    int pair = blockIdx.y, n0 = blockIdx.x * 64, tid = threadIdx.x;
    int b = pair >> 2, w = pair & 3;
    for (int e = tid; e < 512; e += 256) {
        int e4 = e * 4;
        int dn = e4 >> 5, dq = e4 & 31;
        float4 p = *(const float4*)&pc[((size_t)b * NPTS + n0 + dn) * DIM + dq];
        float4 al = *(const float4*)&alphas[w * DIM + dq];
        float4 x = make_float4(p.x * al.x, p.y * al.y, p.z * al.z, p.w * al.w);
        size_t ro = ((size_t)pair * NPTS + n0 + dn) * DIM + dq;
        *(float4*)&X[ro] = x;
        ushort4v xh, xl;
        float xv[4] = {x.x, x.y, x.z, x.w};
#pragma unroll
        for (int j = 0; j < 4; j++) {
            u16 hb = bf16_rne(xv[j]);
            xh[j] = hb;
            xl[j] = bf16_rne(xv[j] - bf16_to_f32(hb));
        }
        *(ushort4v*)(Xbh + ro) = xh;
        *(ushort4v*)(Xbl + ro) = xl;
        S[dq][dn] = x.x; S[dq + 1][dn] = x.y; S[dq + 2][dn] = x.z; S[dq + 3][dn] = x.w;
    }
    __syncthreads();
    if (tid < 64) {
        float s = 0.f;
#pragma unroll
        for (int d = 0; d < DIM; d++) { float v = S[d][tid]; s += v * v; }
        sqX[pair * NPTS + n0 + tid] = s;
        deg[pair * NPTS + n0 + tid] = 0.0f;
    }
    if (tid < 64) {
        int h = tid >> 5, d = tid & 31;   // pool group 0
        float s = 0.f;
#pragma unroll
        for (int k = 0; k < 32; k++) s += S[d][h * 32 + k];
        poolP[(((size_t)0 * NPAIR + pair) * 32 + 2 * blockIdx.x + h) * 32 + d] = s;
    }
    for (int idx = tid; idx < DIM * 4; idx += 256) {
        int row = idx >> 2, nq = (idx & 3) * 16;
        ushort8v hv[2], lv[2];
#pragma unroll
        for (int i = 0; i < 16; i++) {
            float v = S[row][nq + i];
            u16 hb = bf16_rne(v);
            hv[i >> 3][i & 7] = hb;
            lv[i >> 3][i & 7] = bf16_rne(v - bf16_to_f32(hb));
        }
        int c0 = n0 + nq;
        int kt = c0 >> 5;
        int q0 = (c0 >> 3) & 3;        // 0 or 2
        int mm = row & 15;
        size_t base = ((((size_t)pair * 2 + (row >> 4)) * 32 + kt) << 9);   // NF=2
        *(ushort8v*)(hiT + base + (size_t)(q0 * 16 + mm) * 8)       = hv[0];
        *(ushort8v*)(hiT + base + (size_t)((q0 + 1) * 16 + mm) * 8) = hv[1];
        *(ushort8v*)(loT + base + (size_t)(q0 * 16 + mm) * 8)       = lv[0];
        *(ushort8v*)(loT + base + (size_t)((q0 + 1) * 16 + mm) * 8) = lv[1];
    }
}

// ============ W_mfma: G = X@X^T via MFMA (hi/lo, ll-term dropped); exp/quant/fragment store ============
// grid 1024: xcd = b&7, pair = xcd*2 + (loc&1), rest = loc>>1: i0 = (rest&15)*64, j0 = (rest>>4)*256
// block 512 = 8 waves: itile = wv&3 (16 rows), jhalf = wv>>2 (128 cols = 8 jtiles)
__global__ __launch_bounds__(512, 4) void W_mfma(const u16* __restrict__ Xbh,
                                                 const u16* __restrict__ Xbl,
                                                 const float* __restrict__ sqX,
                                                 const float* __restrict__ sigp,
                                                 float* __restrict__ deg,
                                                 u8* __restrict__ W8) {
    __shared__ __align__(16) u8 S8[64][264];   // pad 264: 8B-aligned rows, breaks 256B bank alias
    __shared__ float sqiS[64];
    __shared__ float sqjS[256];
    int bid = blockIdx.x;
    int xcd = bid & 7, loc = bid >> 3;
    int pair = xcd * 2 + (loc & 1);
    int rest = loc >> 1;               // 0..63
    int i0 = (rest & 15) * 64;
    int j0 = (rest >> 4) * 256;
    float rsig = -1.0f / (*sigp);
    int tid = threadIdx.x;
    int wv = tid >> 6, lane = tid & 63;
    int m = lane & 15, quad = lane >> 4;

    if (tid < 64) sqiS[tid] = sqX[pair * NPTS + i0 + tid];
    if (tid < 256) sqjS[tid] = sqX[pair * NPTS + j0 + tid];

    int ibl = (wv & 3) * 16;           // block-local i-tile base
    int jh = (wv >> 2) * 128;          // block-local j-half base
    size_t axy = ((size_t)pair * NPTS + i0 + ibl + m) * DIM + quad * 8;
    short8 Ah = *(const short8*)(Xbh + axy);
    short8 Al = *(const short8*)(Xbl + axy);
    float sqi[4];
    __syncthreads();
#pragma unroll
    for (int ii = 0; ii < 4; ii++) sqi[ii] = sqiS[ibl + quad * 4 + ii];

#pragma unroll
    for (int jt = 0; jt < 8; jt++) {
        int jbl = jh + jt * 16;
        size_t bxy = ((size_t)pair * NPTS + j0 + jbl + m) * DIM + quad * 8;
        short8 Bh = *(const short8*)(Xbh + bxy);
        short8 Bl = *(const short8*)(Xbl + bxy);
        f32x4 g = {0.f, 0.f, 0.f, 0.f};
        g = __builtin_amdgcn_mfma_f32_16x16x32_bf16(Ah, Bh, g, 0, 0, 0);
        g = __builtin_amdgcn_mfma_f32_16x16x32_bf16(Ah, Bl, g, 0, 0, 0);
        g = __builtin_amdgcn_mfma_f32_16x16x32_bf16(Al, Bh, g, 0, 0, 0);
        float sqj = sqjS[jbl + m];
#pragma unroll
        for (int ii = 0; ii < 4; ii++) {
            float Dm = sqi[ii] + sqj - 2.0f * g[ii];
            float K = __expf(Dm * rsig);
            float Wv = (K >= 0.5f) ? K : 0.0f;
            unsigned q = (unsigned)fmaf(Wv, 255.0f, 0.5f);   // 0 or 128..255
            S8[ibl + quad * 4 + ii][jbl + m] = (u8)q;
        }
    }
    __syncthreads();

    // repack: fragment-order uint2 stores + quantized deg row-sums
    {
        int i = tid >> 3, t = tid & 7;
        int iglob = i0 + i;
        size_t wbase = (((size_t)pair * 64 + (iglob >> 4)) * 32) << 9;
        int si = 0;
#pragma unroll
        for (int k = 0; k < 4; k++) {
            int j8 = t * 32 + k * 8;
            uint2 w = *(const uint2*)&S8[i][j8];
            si += (int)((w.x & 0xffu) + ((w.x >> 8) & 0xffu) + ((w.x >> 16) & 0xffu) + (w.x >> 24)
                      + (w.y & 0xffu) + ((w.y >> 8) & 0xffu) + ((w.y >> 16) & 0xffu) + (w.y >> 24));
            int jg = j0 + j8;
            size_t o = wbase + ((size_t)(jg >> 5) << 9)
                     + (size_t)(((jg >> 3) & 3) * 16 + (iglob & 15)) * 8;
            *(uint2*)(W8 + o) = w;
        }
        float s = (float)si;
        s += __shfl_xor(s, 1); s += __shfl_xor(s, 2); s += __shfl_xor(s, 4);
        if (t == 0) atomicAdd(&deg[pair * NPTS + iglob], s);
    }
}

// ============ apply (DC=32, 32-row blocks, grid 512) — unchanged proven A-chain kernel ============
template <int DC>
__global__ __launch_bounds__(512, 4) void apply_fused(const u8* __restrict__ W8,
                                                      const u16* __restrict__ Yhi,
                                                      const u16* __restrict__ Ylo,
                                                      const float* __restrict__ deg,
                                                      const float* __restrict__ prevF,
                                                      int prevStride, int prevOff,
                                                      float* __restrict__ dstF,
                                                      int dstStride, int dstOff,
                                                      float* __restrict__ sliceF,
                                                      u16* __restrict__ hiT, u16* __restrict__ loT,
                                                      int tC0, int tCN) {
    constexpr int NT = DC / 16;
    constexpr int SP = DC + 4;
    __shared__ float S[4][32][SP];
    __shared__ float rdegS[32];
    int bid = blockIdx.x;
    int pair = (bid & 7) * 2 + ((bid >> 3) & 1);
    int r0 = (bid >> 4) * 32;
    int tid = threadIdx.x;
    int wv = tid >> 6, lane = tid & 63;
    int m = lane & 15, quad = lane >> 4;

    if (tid < 32) rdegS[tid] = 0.5f / deg[pair * NPTS + r0 + tid];

    int rt0 = (bid >> 4) * 2;
    const u8*  Wb  = W8  + ((((size_t)pair * 64 + rt0) * 32 + wv * 4) << 9) + (size_t)lane * 8;
    const u16* Ybh = Yhi + (((size_t)pair * NT * 32 + wv * 4) << 9) + (size_t)lane * 8;
    const u16* Ybl = Ylo + (((size_t)pair * NT * 32 + wv * 4) << 9) + (size_t)lane * 8;

    f32x4 acc[2][NT];
#pragma unroll
    for (int mt = 0; mt < 2; mt++)
#pragma unroll
        for (int nt = 0; nt < NT; nt++)
#pragma unroll
            for (int i = 0; i < 4; i++) acc[mt][nt][i] = 0.0f;

#pragma unroll 2
    for (int c = 0; c < 4; c++) {
        uint2 a0q = *(const uint2*)(Wb + ((size_t)c << 9));
        uint2 a1q = *(const uint2*)(Wb + ((size_t)(32 + c) << 9));
        short8 a0h = unpack_w8(a0q.x, a0q.y);
        short8 a1h = unpack_w8(a1q.x, a1q.y);
#pragma unroll
        for (int nt = 0; nt < NT; nt++) {
            short8 bh = *(const short8*)(Ybh + ((size_t)(nt * 32 + c) << 9));
            short8 bl = *(const short8*)(Ybl + ((size_t)(nt * 32 + c) << 9));
            acc[0][nt] = __builtin_amdgcn_mfma_f32_16x16x32_bf16(a0h, bh, acc[0][nt], 0, 0, 0);
            acc[0][nt] = __builtin_amdgcn_mfma_f32_16x16x32_bf16(a0h, bl, acc[0][nt], 0, 0, 0);
            acc[1][nt] = __builtin_amdgcn_mfma_f32_16x16x32_bf16(a1h, bh, acc[1][nt], 0, 0, 0);
            acc[1][nt] = __builtin_amdgcn_mfma_f32_16x16x32_bf16(a1h, bl, acc[1][nt], 0, 0, 0);
        }
    }

    if (wv < 4) {
#pragma unroll
        for (int mt = 0; mt < 2; mt++)
#pragma unroll
            for (int nt = 0; nt < NT; nt++)
#pragma unroll
                for (int i = 0; i < 4; i++)
                    S[wv][mt * 16 + quad * 4 + i][nt * 16 + m] = acc[mt][nt][i];
    }
    __syncthreads();
    if (wv >= 4) {
#pragma unroll
        for (int mt = 0; mt < 2; mt++)
#pragma unroll
            for (int nt = 0; nt < NT; nt++)
#pragma unroll
                for (int i = 0; i < 4; i++)
                    S[wv - 4][mt * 16 + quad * 4 + i][nt * 16 + m] += acc[mt][nt][i];
    }
    __syncthreads();

    constexpr int E2 = 32 * DC / 4;
    for (int e = tid; e < E2; e += 512) {
        int e4 = e * 4;
        int n = e4 / DC, d = e4 % DC;
        float4 s0 = *(const float4*)&S[0][n][d];
        float4 s1 = *(const float4*)&S[1][n][d];
        float4 s2 = *(const float4*)&S[2][n][d];
        float4 s3 = *(const float4*)&S[3][n][d];
        float4 pv = *(const float4*)&prevF[((size_t)pair * NPTS + r0 + n) * prevStride + prevOff + d];
        float r = rdegS[n];
        float4 o = make_float4(0.5f * pv.x + r * (s0.x + s1.x + s2.x + s3.x),
                               0.5f * pv.y + r * (s0.y + s1.y + s2.y + s3.y),
                               0.5f * pv.z + r * (s0.z + s1.z + s2.z + s3.z),
                               0.5f * pv.w + r * (s0.w + s1.w + s2.w + s3.w));
        *(float4*)&dstF[((size_t)pair * NPTS + r0 + n) * dstStride + dstOff + d] = o;
        if (sliceF && d >= 32 && d < 64)
            *(float4*)&sliceF[((size_t)pair * NPTS + r0 + n) * 32 + (d - 32)] = o;
        *(float4*)&S[0][n][d] = o;
    }
    __syncthreads();

    if (hiT) {
        int NFo = tCN >> 4;
        for (int e = tid; e < tCN * 4; e += 512) {
            int row = e >> 2, nq = (e & 3) * 8;
            ushort8v hv, lv;
#pragma unroll
            for (int j = 0; j < 8; j++) {
                float v = S[0][nq + j][tC0 + row];
                u16 hb = bf16_rne(v);
                hv[j] = hb;
                lv[j] = bf16_rne(v - bf16_to_f32(hb));
            }
            int c0 = r0 + nq;
            size_t o = ((((size_t)pair * NFo + (row >> 4)) * 32 + (c0 >> 5)) << 9)
                     + (size_t)((((c0 >> 3) & 3) * 16 + (row & 15))) * 8;
            *(ushort8v*)(hiT + o) = hv;
            *(ushort8v*)(loT + o) = lv;
        }
    }
}

// ============ apply2: 64-row x 32-col chunk blocks (AI=64, halved B traffic) ============
// grid 256*NCH flat: pair = (b&7)*2 + ((b>>3)&1), rseg = (b>>4)&15, chunk = b>>8; block 512
template <int DC>
__global__ __launch_bounds__(512, 4) void apply_fused2(const u8* __restrict__ W8,
                                                       const u16* __restrict__ Yhi,
                                                       const u16* __restrict__ Ylo,
                                                       const float* __restrict__ deg,
                                                       const float* __restrict__ prevF,
                                                       int prevStride, int prevOff,
                                                       float* __restrict__ dstF,
                                                       int dstStride, int dstOff,
                                                       float* __restrict__ sliceF,  // cols 32..63 (chunk 1)
                                                       u16* __restrict__ hiT, u16* __restrict__ loT,
                                                       int tC0, int tCN) {
    constexpr int NF = DC / 16;
    constexpr int SP = 36;
    __shared__ float S[4][64][SP];
    __shared__ float rdegS[64];
    int bid = blockIdx.x;
    int pair = (bid & 7) * 2 + ((bid >> 3) & 1);
    int rseg = (bid >> 4) & 15;
    int ch = bid >> 8;
    int r0 = rseg * 64;
    int tid = threadIdx.x;
    int wv = tid >> 6, lane = tid & 63;
    int m = lane & 15, quad = lane >> 4;

    if (tid < 64) rdegS[tid] = 0.5f / deg[pair * NPTS + r0 + tid];

    const u8*  Wb  = W8  + ((((size_t)pair * 64 + rseg * 4) * 32 + wv * 4) << 9) + (size_t)lane * 8;
    const u16* Ybh = Yhi + ((((size_t)pair * NF + ch * 2) * 32 + wv * 4) << 9) + (size_t)lane * 8;
    const u16* Ybl = Ylo + ((((size_t)pair * NF + ch * 2) * 32 + wv * 4) << 9) + (size_t)lane * 8;

    f32x4 acc[4][2];
#pragma unroll
    for (int mt = 0; mt < 4; mt++)
#pragma unroll
        for (int nt = 0; nt < 2; nt++)
#pragma unroll
            for (int i = 0; i < 4; i++) acc[mt][nt][i] = 0.0f;

#pragma unroll 2
    for (int c = 0; c < 4; c++) {
        uint2 aq[4];
#pragma unroll
        for (int mt = 0; mt < 4; mt++)
            aq[mt] = *(const uint2*)(Wb + ((size_t)(mt * 32 + c) << 9));
        short8 a[4];
#pragma unroll
        for (int mt = 0; mt < 4; mt++) a[mt] = unpack_w8(aq[mt].x, aq[mt].y);
#pragma unroll
        for (int nt = 0; nt < 2; nt++) {
            short8 bh = *(const short8*)(Ybh + ((size_t)(nt * 32 + c) << 9));
            short8 bl = *(const short8*)(Ybl + ((size_t)(nt * 32 + c) << 9));
#pragma unroll
            for (int mt = 0; mt < 4; mt++) {
                acc[mt][nt] = __builtin_amdgcn_mfma_f32_16x16x32_bf16(a[mt], bh, acc[mt][nt], 0, 0, 0);
                acc[mt][nt] = __builtin_amdgcn_mfma_f32_16x16x32_bf16(a[mt], bl, acc[mt][nt], 0, 0, 0);
            }
        }
    }

    // phase 1a: waves 0-3 deposit partial tiles (64 rows x 32 cols)
    if (wv < 4) {
#pragma unroll
        for (int mt = 0; mt < 4; mt++)
#pragma unroll
            for (int nt = 0; nt < 2; nt++)
#pragma unroll
                for (int i = 0; i < 4; i++)
                    S[wv][mt * 16 + quad * 4 + i][nt * 16 + m] = acc[mt][nt][i];
    }
    __syncthreads();
    // phase 1b: waves 4-7 add into planes 0-3
    if (wv >= 4) {
#pragma unroll
        for (int mt = 0; mt < 4; mt++)
#pragma unroll
            for (int nt = 0; nt < 2; nt++)
#pragma unroll
                for (int i = 0; i < 4; i++)
                    S[wv - 4][mt * 16 + quad * 4 + i][nt * 16 + m] += acc[mt][nt][i];
    }
    __syncthreads();

    // phase 2: one float4 per thread (64 rows x 32 cols / 4)
    {
        int n = tid >> 3, d = (tid & 7) * 4;
        int col = ch * 32 + d;
        float4 s0 = *(const float4*)&S[0][n][d];
        float4 s1 = *(const float4*)&S[1][n][d];
        float4 s2 = *(const float4*)&S[2][n][d];
        float4 s3 = *(const float4*)&S[3][n][d];
        float4 pv = *(const float4*)&prevF[((size_t)pair * NPTS + r0 + n) * prevStride + prevOff + col];
        float r = rdegS[n];
        float4 o = make_float4(0.5f * pv.x + r * (s0.x + s1.x + s2.x + s3.x),
                               0.5f * pv.y + r * (s0.y + s1.y + s2.y + s3.y),
                               0.5f * pv.z + r * (s0.z + s1.z + s2.z + s3.z),
                               0.5f * pv.w + r * (s0.w + s1.w + s2.w + s3.w));
        *(float4*)&dstF[((size_t)pair * NPTS + r0 + n) * dstStride + dstOff + col] = o;
        if (sliceF && ch == 1)
            *(float4*)&sliceF[((size_t)pair * NPTS + r0 + n) * 32 + d] = o;
        *(float4*)&S[0][n][d] = o;
    }
    __syncthreads();

    // phase 3: transposed bf16 hi/lo for this chunk's 32 feature rows (if in T range)
    int gr0 = 32 * ch - tC0;
    if (hiT && gr0 >= 0 && gr0 < tCN) {
        int NFo = tCN >> 4;
        if (tid < 256) {
            int lr = tid >> 3, nq = (tid & 7) * 8;
            ushort8v hv, lv;
#pragma unroll
            for (int j = 0; j < 8; j++) {
                float v = S[0][nq + j][lr];
                u16 hb = bf16_rne(v);
                hv[j] = hb;
                lv[j] = bf16_rne(v - bf16_to_f32(hb));
            }
            int gr = gr0 + lr;
            int c0 = r0 + nq;
            size_t o = ((((size_t)pair * NFo + (gr >> 4)) * 32 + (c0 >> 5)) << 9)
                     + (size_t)((((c0 >> 3) & 3) * 16 + (gr & 15))) * 8;
            *(ushort8v*)(hiT + o) = hv;
            *(ushort8v*)(loT + o) = lv;
        }
    }
}

// ============ fat apply A4 (DC=32, 32-row blocks, grid 512) — unchanged proven kernel ============
__global__ __launch_bounds__(512, 4) void apply_fused_m0(const u8* __restrict__ W8,
                                                         const u16* __restrict__ Yhi,
                                                         const u16* __restrict__ Ylo,
                                                         const float* __restrict__ deg,
                                                         const float* __restrict__ prevF,   // A3, stride 32
                                                         const float* __restrict__ A1,
                                                         const float* __restrict__ A2,
                                                         float* __restrict__ M0,            // stride 96
                                                         u16* __restrict__ hiT, u16* __restrict__ loT,  // T96a
                                                         float* __restrict__ poolP) {
    constexpr int DC = 32, NT = 2, SP = 36;
    __shared__ float S[4][32][SP];
    __shared__ float rdegS[32];
    __shared__ float SB[96][33];
    int bid = blockIdx.x;
    int pair = (bid & 7) * 2 + ((bid >> 3) & 1);
    int r0 = (bid >> 4) * 32;
    int rt = bid >> 4;
    int tid = threadIdx.x;
    int wv = tid >> 6, lane = tid & 63;
    int m = lane & 15, quad = lane >> 4;

    if (tid < 32) rdegS[tid] = 0.5f / deg[pair * NPTS + r0 + tid];

    int rt0 = rt * 2;
    const u8*  Wb  = W8  + ((((size_t)pair * 64 + rt0) * 32 + wv * 4) << 9) + (size_t)lane * 8;
    const u16* Ybh = Yhi + (((size_t)pair * NT * 32 + wv * 4) << 9) + (size_t)lane * 8;
    const u16* Ybl = Ylo + (((size_t)pair * NT * 32 + wv * 4) << 9) + (size_t)lane * 8;

    f32x4 acc[2][NT];
#pragma unroll
    for (int mt = 0; mt < 2; mt++)
#pragma unroll
        for (int nt = 0; nt < NT; nt++)
#pragma unroll
            for (int i = 0; i < 4; i++) acc[mt][nt][i] = 0.0f;

#pragma unroll 2
    for (int c = 0; c < 4; c++) {
        uint2 a0q = *(const uint2*)(Wb + ((size_t)c << 9));
        uint2 a1q = *(const uint2*)(Wb + ((size_t)(32 + c) << 9));
        short8 a0h = unpack_w8(a0q.x, a0q.y);
        short8 a1h = unpack_w8(a1q.x, a1q.y);
#pragma unroll
        for (int nt = 0; nt < NT; nt++) {
            short8 bh = *(const short8*)(Ybh + ((size_t)(nt * 32 + c) << 9));
            short8 bl = *(const short8*)(Ybl + ((size_t)(nt * 32 + c) << 9));
            acc[0][nt] = __builtin_amdgcn_mfma_f32_16x16x32_bf16(a0h, bh, acc[0][nt], 0, 0, 0);
            acc[0][nt] = __builtin_amdgcn_mfma_f32_16x16x32_bf16(a0h, bl, acc[0][nt], 0, 0, 0);
            acc[1][nt] = __builtin_amdgcn_mfma_f32_16x16x32_bf16(a1h, bh, acc[1][nt], 0, 0, 0);
            acc[1][nt] = __builtin_amdgcn_mfma_f32_16x16x32_bf16(a1h, bl, acc[1][nt], 0, 0, 0);
        }
    }

    if (wv < 4) {
#pragma unroll
        for (int mt = 0; mt < 2; mt++)
#pragma unroll
            for (int nt = 0; nt < NT; nt++)
#pragma unroll
                for (int i = 0; i < 4; i++)
                    S[wv][mt * 16 + quad * 4 + i][nt * 16 + m] = acc[mt][nt][i];
    }
    __syncthreads();
    if (wv >= 4) {
#pragma unroll
        for (int mt = 0; mt < 2; mt++)
#pragma unroll
            for (int nt = 0; nt < NT; nt++)
#pragma unroll
                for (int i = 0; i < 4; i++)
                    S[wv - 4][mt * 16 + quad * 4 + i][nt * 16 + m] += acc[mt][nt][i];
    }
    __syncthreads();

    for (int e = tid; e < 256; e += 512) {
        int e4 = e * 4;
        int n = e4 / DC, d = e4 % DC;
        float4 s0 = *(const float4*)&S[0][n][d];
        float4 s1 = *(const float4*)&S[1][n][d];
        float4 s2 = *(const float4*)&S[2][n][d];
        float4 s3 = *(const float4*)&S[3][n][d];
        float4 pv = *(const float4*)&prevF[((size_t)pair * NPTS + r0 + n) * 32 + d];
        float r = rdegS[n];
        float4 o = make_float4(0.5f * pv.x + r * (s0.x + s1.x + s2.x + s3.x),
                               0.5f * pv.y + r * (s0.y + s1.y + s2.y + s3.y),
                               0.5f * pv.z + r * (s0.z + s1.z + s2.z + s3.z),
                               0.5f * pv.w + r * (s0.w + s1.w + s2.w + s3.w));
        *(float4*)&M0[((size_t)pair * NPTS + r0 + n) * 96 + d] = o;
        *(float4*)&S[0][n][d] = o;
    }
    __syncthreads();

    if (tid < 256) {
        int dn = tid >> 3, dq = (tid & 7) * 4;
        size_t pn = (size_t)pair * NPTS + r0 + dn;
        float4 a1 = *(const float4*)&A1[pn * 32 + dq];
        float4 a2 = *(const float4*)&A2[pn * 32 + dq];
        float4 t4 = *(const float4*)&S[0][dn][dq];
        float4 f0 = make_float4(fabsf(a1.x - a2.x), fabsf(a1.y - a2.y), fabsf(a1.z - a2.z), fabsf(a1.w - a2.w));
        float4 f1 = make_float4(fabsf(a2.x - t4.x), fabsf(a2.y - t4.y), fabsf(a2.z - t4.z), fabsf(a2.w - t4.w));
        *(float4*)&M0[pn * 96 + 32 + dq] = f0;
        *(float4*)&M0[pn * 96 + 64 + dq] = f1;
        SB[dq][dn] = t4.x; SB[dq + 1][dn] = t4.y; SB[dq + 2][dn] = t4.z; SB[dq + 3][dn] = t4.w;
        SB[32 + dq][dn] = f0.x; SB[33 + dq][dn] = f0.y; SB[34 + dq][dn] = f0.z; SB[35 + dq][dn] = f0.w;
        SB[64 + dq][dn] = f1.x; SB[65 + dq][dn] = f1.y; SB[66 + dq][dn] = f1.z; SB[67 + dq][dn] = f1.w;
    }
    __syncthreads();

    if (tid < 64) {
        int gg = tid >> 5, d = tid & 31;
        float s = 0.f;
#pragma unroll
        for (int k = 0; k < 32; k++) s += SB[32 + gg * 32 + d][k];
        poolP[(((size_t)(1 + gg) * NPAIR + pair) * 32 + rt) * 32 + d] = s;
    }

    for (int e = tid; e < 96 * 4; e += 512) {
        int row = e >> 2, nq = (e & 3) * 8;
        ushort8v hv, lv;
#pragma unroll
        for (int j = 0; j < 8; j++) {
            float v = SB[row][nq + j];
            u16 hb = bf16_rne(v);
            hv[j] = hb;
            lv[j] = bf16_rne(v - bf16_to_f32(hb));
        }
        int c0 = r0 + nq;
        size_t o = ((((size_t)pair * 6 + (row >> 4)) * 32 + (c0 >> 5)) << 9)
                 + (size_t)((((c0 >> 3) & 3) * 16 + (row & 15))) * 8;
        *(ushort8v*)(hiT + o) = hv;
        *(ushort8v*)(loT + o) = lv;
    }
}

// ============ fat apply N4: apply2<64> core -> Z8, + pool groups 3..6 ============
// grid 512 (= 256 x 2 chunks): ch0 blocks do groups 3,4,5; ch1 blocks do group 6
__global__ __launch_bounds__(512, 4) void apply_fused_pool2(const u8* __restrict__ W8,
                                                            const u16* __restrict__ Yhi,
                                                            const u16* __restrict__ Ylo,
                                                            const float* __restrict__ deg,
                                                            const float* __restrict__ prevF,  // F96a, stride 64
                                                            float* __restrict__ Z8,           // stride 64
                                                            const float* __restrict__ M0,
                                                            const float* __restrict__ M2p,
                                                            const float* __restrict__ M4f,
                                                            float* __restrict__ poolP) {
    constexpr int NF = 4, SP = 36;
    __shared__ float S[4][64][SP];
    __shared__ float rdegS[64];
    int bid = blockIdx.x;
    int pair = (bid & 7) * 2 + ((bid >> 3) & 1);
    int rseg = (bid >> 4) & 15;
    int ch = bid >> 8;
    int r0 = rseg * 64;
    int tid = threadIdx.x;
    int wv = tid >> 6, lane = tid & 63;
    int m = lane & 15, quad = lane >> 4;

    if (tid < 64) rdegS[tid] = 0.5f / deg[pair * NPTS + r0 + tid];

    const u8*  Wb  = W8  + ((((size_t)pair * 64 + rseg * 4) * 32 + wv * 4) << 9) + (size_t)lane * 8;
    const u16* Ybh = Yhi + ((((size_t)pair * NF + ch * 2) * 32 + wv * 4) << 9) + (size_t)lane * 8;
    const u16* Ybl = Ylo + ((((size_t)pair * NF + ch * 2) * 32 + wv * 4) << 9) + (size_t)lane * 8;

    f32x4 acc[4][2];
#pragma unroll
    for (int mt = 0; mt < 4; mt++)
#pragma unroll
        for (int nt = 0; nt < 2; nt++)
#pragma unroll
            for (int i = 0; i < 4; i++) acc[mt][nt][i] = 0.0f;

#pragma unroll 2
    for (int c = 0; c < 4; c++) {
        uint2 aq[4];
#pragma unroll
        for (int mt = 0; mt < 4; mt++)
            aq[mt] = *(const uint2*)(Wb + ((size_t)(mt * 32 + c) << 9));
        short8 a[4];
#pragma unroll
        for (int mt = 0; mt < 4; mt++) a[mt] = unpack_w8(aq[mt].x, aq[mt].y);
#pragma unroll
        for (int nt = 0; nt < 2; nt++) {
            short8 bh = *(const short8*)(Ybh + ((size_t)(nt * 32 + c) << 9));
            short8 bl = *(const short8*)(Ybl + ((size_t)(nt * 32 + c) << 9));
#pragma unroll
            for (int mt = 0; mt < 4; mt++) {
                acc[mt][nt] = __builtin_amdgcn_mfma_f32_16x16x32_bf16(a[mt], bh, acc[mt][nt], 0, 0, 0);
                acc[mt][nt] = __builtin_amdgcn_mfma_f32_16x16x32_bf16(a[mt], bl, acc[mt][nt], 0, 0, 0);
            }
        }
    }

    if (wv < 4) {
#pragma unroll
        for (int mt = 0; mt < 4; mt++)
#pragma unroll
            for (int nt = 0; nt < 2; nt++)
#pragma unroll
                for (int i = 0; i < 4; i++)
                    S[wv][mt * 16 + quad * 4 + i][nt * 16 + m] = acc[mt][nt][i];
    }
    __syncthreads();
    if (wv >= 4) {
#pragma unroll
        for (int mt = 0; mt < 4; mt++)
#pragma unroll
            for (int nt = 0; nt < 2; nt++)
#pragma unroll
                for (int i = 0; i < 4; i++)
                    S[wv - 4][mt * 16 + quad * 4 + i][nt * 16 + m] += acc[mt][nt][i];
    }
    __syncthreads();

    {
        int n = tid >> 3, d = (tid & 7) * 4;
        int col = ch * 32 + d;
        float4 s0 = *(const float4*)&S[0][n][d];
        float4 s1 = *(const float4*)&S[1][n][d];
        float4 s2 = *(const float4*)&S[2][n][d];
        float4 s3 = *(const float4*)&S[3][n][d];
        float4 pv = *(const float4*)&prevF[((size_t)pair * NPTS + r0 + n) * 64 + col];
        float r = rdegS[n];
        float4 o = make_float4(0.5f * pv.x + r * (s0.x + s1.x + s2.x + s3.x),
                               0.5f * pv.y + r * (s0.y + s1.y + s2.y + s3.y),
                               0.5f * pv.z + r * (s0.z + s1.z + s2.z + s3.z),
                               0.5f * pv.w + r * (s0.w + s1.w + s2.w + s3.w));
        *(float4*)&Z8[((size_t)pair * NPTS + r0 + n) * 64 + col] = o;
        *(float4*)&S[0][n][d] = o;
    }
    __syncthreads();

    // pool partials: per 32-point half h -> slot 2*rseg + h (keeps poolP layout at 32 slots)
    if (ch == 0) {
        if (tid < 192) {
            int gsel = tid >> 6, h = (tid >> 5) & 1, d = tid & 31;
            float s = 0.f;
#pragma unroll 4
            for (int k = 0; k < 32; k++) {
                int n = h * 32 + k;
                size_t pn = (size_t)pair * NPTS + r0 + n;
                float v;
                switch (gsel) {
                    case 0: v = fabsf(M0[pn * 96 + d] - M4f[pn * 96 + d]); break;
                    case 1: v = fabsf(M2p[pn * 32 + d] - M4f[pn * 96 + 32 + d]); break;
                    default: v = fabsf(M4f[pn * 96 + 32 + d] - S[0][n][d]); break;
                }
                s += v;
            }
            poolP[(((size_t)(3 + gsel) * NPAIR + pair) * 32 + 2 * rseg + h) * 32 + d] = s;
        }
    } else {
        if (tid < 64) {
            int h = tid >> 5, d = tid & 31;
            float s = 0.f;
#pragma unroll 4
            for (int k = 0; k < 32; k++) {
                int n = h * 32 + k;
                size_t pn = (size_t)pair * NPTS + r0 + n;
                s += fabsf(M4f[pn * 96 + 64 + d] - S[0][n][d]);   // S[0] holds Z8 cols 32..63
            }
            poolP[(((size_t)6 * NPAIR + pair) * 32 + 2 * rseg + h) * 32 + d] = s;
        }
    }
}

// ============ pool final: grid (NPAIR), block 256; reduce 32 slot partials ============
__global__ __launch_bounds__(256) void pool_final(const float* __restrict__ partial,
                                                  float* __restrict__ out) {
    int pair = blockIdx.x;
    int t = threadIdx.x;
    if (t < 224) {
        int g = t >> 5, d = t & 31;
        float s = 0.0f;
#pragma unroll 8
        for (int r = 0; r < 32; r++)
            s += partial[(((size_t)g * NPAIR + pair) * 32 + r) * 32 + d];
        out[(size_t)pair * 224 + t] = s * (1.0f / 1024.0f);
    }
}

extern "C" void kernel_launch(void* const* d_in, const int* in_sizes, int n_in,
                              void* d_out, int out_size, void* d_ws, size_t ws_size,
                              hipStream_t stream) {
    const float* pc     = (const float*)d_in[0];
    const float* alphas = (const float*)d_in[1];
    const float* sigp   = (const float*)d_in[2];
    float* out = (float*)d_out;
    float* ws = (float*)d_ws;

    // ---- workspace layout (W8/T* fragment-ordered; + Xb hi/lo bf16 row panels) ----
    float* X    = ws;                         // 524288
    float* sqX  = X + 524288;                 // 16384
    float* deg  = sqX + 16384;                // 16384
    u8* W8 = (u8*)(deg + 16384);              // 16777216 u8
    float* A1   = (float*)(W8 + 16777216);    // 524288
    float* A2   = A1 + 524288;                // 524288
    u16* T32a_h = (u16*)(A2 + 524288);        // 524288 u16 each
    u16* T32a_l = T32a_h + 524288;
    u16* T32b_h = T32a_l + 524288;
    u16* T32b_l = T32b_h + 524288;
    float* F96b = A1;                         // overlay (A1,A2,T32a_h/l dead by then)
    float* M0   = (float*)(T32b_l + 524288);  // 1572864
    float* M2p  = M0 + 1572864;               // 524288
    float* M4f  = M2p + 524288;               // 1572864
    float* Z8   = M4f + 1572864;              // 1048576
    float* F96a = Z8 + 1048576;               // 1572864  (also A3 overlay before M-chain)
    float* A3   = F96a;
    u16* T96a_h = (u16*)(F96a + 1572864);     // 1572864 u16 each
    u16* T96a_l = T96a_h + 1572864;
    u16* T96b_h = T96a_l + 1572864;
    u16* T96b_l = T96b_h + 1572864;
    u16* T64a_h = T96a_h;
    u16* T64a_l = T96a_l;
    u16* T64b_h = T96b_h;
    u16* T64b_l = T96b_l;
    float* poolP = (float*)(T96b_l + 1572864); // 7*16*32*32 = 114688 floats
    u16* Xbh = (u16*)(poolP + 114688);         // 524288 u16 each (row-major bf16 X hi/lo)
    u16* Xbl = Xbh + 524288;

    dim3 b256(256), b512(512);

    build_X<<<dim3(16, NPAIR), b256, 0, stream>>>(pc, alphas, X, Xbh, Xbl, sqX, deg, T32a_h, T32a_l, poolP);
    W_mfma<<<dim3(1024), b512, 0, stream>>>(Xbh, Xbl, sqX, sigp, deg, W8);

    // ---- A-chain (D=32): unchanged 32-row kernels ----
    apply_fused<32><<<dim3(512), b512, 0, stream>>>(W8, T32a_h, T32a_l, deg,
                                             X, 32, 0, A1, 32, 0, nullptr, T32b_h, T32b_l, 0, 32);
    apply_fused<32><<<dim3(512), b512, 0, stream>>>(W8, T32b_h, T32b_l, deg,
                                             A1, 32, 0, A2, 32, 0, nullptr, T32a_h, T32a_l, 0, 32);
    apply_fused<32><<<dim3(512), b512, 0, stream>>>(W8, T32a_h, T32a_l, deg,
                                             A2, 32, 0, A3, 32, 0, nullptr, T32b_h, T32b_l, 0, 32);
    apply_fused_m0<<<dim3(512), b512, 0, stream>>>(W8, T32b_h, T32b_l, deg,
                                             A3, A1, A2, M0, T96a_h, T96a_l, poolP);

    // ---- M-chain (D=96): 64-row chunk-split, grid 768 ----
    apply_fused2<96><<<dim3(768), b512, 0, stream>>>(W8, T96a_h, T96a_l, deg,
                                             M0, 96, 0, F96a, 96, 0, nullptr, T96b_h, T96b_l, 0, 96);
    apply_fused2<96><<<dim3(768), b512, 0, stream>>>(W8, T96b_h, T96b_l, deg,
                                             F96a, 96, 0, F96b, 96, 0, M2p, T96a_h, T96a_l, 0, 96);
    apply_fused2<96><<<dim3(768), b512, 0, stream>>>(W8, T96a_h, T96a_l, deg,
                                             F96b, 96, 0, F96a, 96, 0, nullptr, T96b_h, T96b_l, 0, 96);
    apply_fused2<96><<<dim3(768), b512, 0, stream>>>(W8, T96b_h, T96b_l, deg,
                                             F96a, 96, 0, M4f, 96, 0, nullptr, T64a_h, T64a_l, 32, 64);

    // ---- N-chain (D=64): 64-row chunk-split, grid 512 ----
    apply_fused2<64><<<dim3(512), b512, 0, stream>>>(W8, T64a_h, T64a_l, deg,
                                             M4f, 96, 32, F96a, 64, 0, nullptr, T64b_h, T64b_l, 0, 64);
    apply_fused2<64><<<dim3(512), b512, 0, stream>>>(W8, T64b_h, T64b_l, deg,
                                             F96a, 64, 0, F96b, 64, 0, nullptr, T64a_h, T64a_l, 0, 64);
    apply_fused2<64><<<dim3(512), b512, 0, stream>>>(W8, T64a_h, T64a_l, deg,
                                             F96b, 64, 0, F96a, 64, 0, nullptr, T64b_h, T64b_l, 0, 64);
    apply_fused_pool2<<<dim3(512), b512, 0, stream>>>(W8, T64b_h, T64b_l, deg,
                                             F96a, Z8, M0, M2p, M4f, poolP);

    pool_final<<<dim3(NPAIR), b256, 0, stream>>>(poolP, out);
}